// Round 6
// baseline (672.013 us; speedup 1.0000x reference)
//
#include <hip/hip_runtime.h>

// ---------------------------------------------------------------------------
// Att_MambaLayer: bf16-MFMA everywhere + fused BC/dt GEMM + chunked scan.
// B=4, C=256, H=W=32, N=l=1024, NH=2, dh=128, DI=512, DS=16, DTR=16.
// ---------------------------------------------------------------------------

#define LOG2E 1.4426950408889634f
#define NCH 16
#define LCH 64

typedef unsigned short u16;
typedef unsigned int u32;
typedef __attribute__((ext_vector_type(8))) short bf16x8;
typedef __attribute__((ext_vector_type(4))) float f32x4;

__device__ __forceinline__ u16 f2b(float f) {
  u32 u = __builtin_bit_cast(u32, f);
  u32 r = (u + 0x7fffu + ((u >> 16) & 1u)) >> 16;
  return (u16)r;
}
__device__ __forceinline__ float b2f(u16 h) {
  u32 u = ((u32)h) << 16;
  return __builtin_bit_cast(float, u);
}

#define DPP_ADD(p, ctrl)                                                   \
  (p) += __builtin_bit_cast(float, __builtin_amdgcn_update_dpp(            \
             0, __builtin_bit_cast(int, (p)), ctrl, 0xF, 0xF, true))

static const long BRS = 44544;

// ---- param packing --------------------------------------------------------
struct BrP { const float *cw, *cb, *xpw, *dtw, *dtb, *Al, *Dv; };

__global__ __launch_bounds__(256) void pack_branch_k(float* __restrict__ dst0,
                                                     BrP p0, BrP p1, BrP p2) {
  int z = blockIdx.y;
  BrP p = (z == 0) ? p0 : ((z == 1) ? p1 : p2);
  float* dst = dst0 + (long)z * BRS;
  int t = blockIdx.x * 256 + threadIdx.x;
  if (t < 2048) dst[t] = p.cw[t];
  else if (t < 2560) dst[t] = p.cb[t - 2048];
  else if (t < 27136) dst[t] = p.xpw[t - 2560];
  else if (t < 35328) dst[t] = p.dtw[t - 27136];
  else if (t < 35840) dst[t] = p.dtb[t - 35328];
  else if (t < 44032) dst[t] = -expf(p.Al[t - 35840]) * LOG2E;
  else if (t < 44544) dst[t] = p.Dv[t - 44032];
}

__global__ __launch_bounds__(256) void pack_wb_k(
    const float* __restrict__ qw, const float* __restrict__ kw,
    const float* __restrict__ vw, const float* __restrict__ ow,
    const float* __restrict__ inw, const float* __restrict__ outw,
    const float* __restrict__ p2w, const float* __restrict__ fc1w,
    const float* __restrict__ qb, const float* __restrict__ kb,
    const float* __restrict__ vb, u16* __restrict__ WB,
    float* __restrict__ QBIAS) {
  int t = blockIdx.x * 256 + threadIdx.x;   // < 787,200
  if (t < 65536) WB[t] = f2b(qw[t]);
  else if (t < 131072) WB[t] = f2b(kw[t - 65536]);
  else if (t < 196608) WB[t] = f2b(vw[t - 131072]);
  else if (t < 262144) WB[t] = f2b(ow[t - 196608]);
  else if (t < 524288) WB[t] = f2b(inw[t - 262144]);
  else if (t < 655360) WB[t] = f2b(outw[t - 524288]);
  else if (t < 720896) WB[t] = f2b(p2w[t - 655360]);
  else if (t < 786432) WB[t] = f2b(fc1w[t - 720896]);
  else if (t < 787200) {
    int i = t - 786432;
    QBIAS[i] = (i < 256) ? qb[i] : (i < 512 ? kb[i - 256] : vb[i - 512]);
  }
}

// conv weight pack: wc[co][(kh*3+kw)*256+ci] = w[co][ci][kh][kw]
__global__ __launch_bounds__(256) void pack_wc_k(const float* __restrict__ w,
                                                 u16* __restrict__ wc) {
  int t = blockIdx.x * 256 + threadIdx.x;   // < 589,824
  int ci = t & 255, khw = (t >> 8) % 9, co = t / 2304;
  wc[t] = f2b(w[co * 2304 + ci * 9 + khw]);
}

// x input -> shuffled NHWC bf16 (the x_flat permutation)
__global__ __launch_bounds__(256) void xin_k(const float* __restrict__ x,
                                             u16* __restrict__ xin) {
  int t = blockIdx.x * 256 + threadIdx.x;   // < 1,048,576
  int ci = t & 255, w = (t >> 8) & 31, h = (t >> 13) & 31, b = t >> 18;
  int idx = ci * 32 + h;
  xin[t] = f2b(x[((long)b << 18) + ((long)(idx & 255) << 10) +
                 ((idx >> 8) << 5) + w]);
}

// WMB rows 0..31 (B,C from xpw rows 16..47), rows 544..639 zero, bias vector
__global__ __launch_bounds__(256) void pack_wmb_k(const float* __restrict__ PB,
                                                  u16* __restrict__ WMB,
                                                  float* __restrict__ BIA) {
  int z = blockIdx.y;
  int t = blockIdx.x * 256 + threadIdx.x;   // < 66,176
  const float* pb = PB + (long)z * BRS;
  if (t < 16384) {
    int r = t >> 9, k = t & 511;
    WMB[((long)z * 640 + r) * 512 + k] = f2b(pb[2560 + (16 + r) * 512 + k]);
  } else if (t < 65536) {
    int i = t - 16384;
    int r = 544 + (i >> 9), k = i & 511;
    WMB[((long)z * 640 + r) * 512 + k] = 0;
  } else if (t < 66176) {
    int i = t - 65536;   // 0..639
    float v = 0.f;
    if (i >= 32 && i < 544) v = pb[35328 + (i - 32)];
    BIA[(long)z * 640 + i] = v;
  }
}

// W_dt = dtw @ xpw[:16]  -> WMB rows 32..543
__global__ __launch_bounds__(256) void pack_wdt_k(const float* __restrict__ PB,
                                                  u16* __restrict__ WMB) {
  int z = blockIdx.y, d = blockIdx.x;
  const float* pb = PB + (long)z * BRS;
  float dtwv[16];
  #pragma unroll
  for (int r = 0; r < 16; ++r) dtwv[r] = pb[27136 + d * 16 + r];
  #pragma unroll
  for (int i = 0; i < 2; ++i) {
    int k = threadIdx.x + i * 256;
    float acc = 0.f;
    #pragma unroll
    for (int r = 0; r < 16; ++r) acc = fmaf(dtwv[r], pb[2560 + r * 512 + k], acc);
    WMB[((long)z * 640 + 32 + d) * 512 + k] = f2b(acc);
  }
}

// ---- MFMA 3x3 conv --------------------------------------------------------
__global__ __launch_bounds__(256, 2) void conv_mfma_k(
    const u16* __restrict__ in, const u16* __restrict__ wc,
    const float* __restrict__ bias, float* __restrict__ outF,
    u16* __restrict__ outH, int relu) {
  __shared__ u16 ldsA[4][64][8];
  __shared__ u16 ldsB[4][64][8];
  int m0 = blockIdx.x * 64, n0 = blockIdx.y * 64;
  int tid = threadIdx.x;
  int lane = tid & 63, wv = tid >> 6;
  int row = tid & 63, k8 = tid >> 6;
  int l = m0 + row;
  int h = (l >> 5) & 31, w = l & 31;
  int rlo = lane & 15, khl = lane >> 4;
  f32x4 acc[4];
  #pragma unroll
  for (int n = 0; n < 4; ++n) acc[n] = (f32x4){0.f, 0.f, 0.f, 0.f};
  for (int t = 0; t < 72; ++t) {
    int kh = t / 24, r = t % 24, kw = r >> 3, ci0 = (r & 7) << 5;
    __syncthreads();
    bf16x8 av = (bf16x8){0, 0, 0, 0, 0, 0, 0, 0};
    int hh = h + kh - 1, ww = w + kw - 1;
    if ((unsigned)hh < 32u && (unsigned)ww < 32u)
      av = *(const bf16x8*)&in[(long)(l + (kh - 1) * 32 + (kw - 1)) * 256 +
                               ci0 + k8 * 8];
    *(bf16x8*)&ldsA[k8][row][0] = av;
    *(bf16x8*)&ldsB[k8][row][0] =
        *(const bf16x8*)&wc[(long)(n0 + row) * 2304 + t * 32 + k8 * 8];
    __syncthreads();
    bf16x8 af = *(const bf16x8*)&ldsA[khl][wv * 16 + rlo][0];
    #pragma unroll
    for (int n = 0; n < 4; ++n) {
      bf16x8 bf = *(const bf16x8*)&ldsB[khl][n * 16 + rlo][0];
      acc[n] = __builtin_amdgcn_mfma_f32_16x16x32_bf16(af, bf, acc[n], 0, 0, 0);
    }
  }
  int rowb = (lane >> 4) * 4;
  #pragma unroll
  for (int n = 0; n < 4; ++n) {
    int gn = n0 + n * 16 + rlo;
    float bv = bias[gn];
    #pragma unroll
    for (int j = 0; j < 4; ++j) {
      int gm = m0 + wv * 16 + rowb + j;
      float v = acc[n][j] + bv;
      if (relu) v = fmaxf(v, 0.f);
      long oi = (long)gm * 256 + gn;
      if (outH) outH[oi] = f2b(v);
      else outF[oi] = v;
    }
  }
}

// ---- LayerNorm rows of 256 -> bf16 (wave per row) -------------------------
__global__ __launch_bounds__(256) void layernorm_k(const float* __restrict__ x,
                                                   const float* __restrict__ w,
                                                   const float* __restrict__ b,
                                                   u16* __restrict__ o) {
  int row = blockIdx.x * 4 + (threadIdx.x >> 6);
  int lane = threadIdx.x & 63;
  float4 v = ((const float4*)(x + (long)row * 256))[lane];
  float s = v.x + v.y + v.z + v.w;
  #pragma unroll
  for (int m = 32; m; m >>= 1) s += __shfl_xor(s, m);
  float mean = s * (1.f / 256.f);
  float4 dv = {v.x - mean, v.y - mean, v.z - mean, v.w - mean};
  float vs = dv.x * dv.x + dv.y * dv.y + dv.z * dv.z + dv.w * dv.w;
  #pragma unroll
  for (int m = 32; m; m >>= 1) vs += __shfl_xor(vs, m);
  float inv = rsqrtf(vs * (1.f / 256.f) + 1e-5f);
  float4 wv = ((const float4*)w)[lane];
  float4 bv = ((const float4*)b)[lane];
  u32 lo = (u32)f2b(dv.x * inv * wv.x + bv.x) |
           ((u32)f2b(dv.y * inv * wv.y + bv.y) << 16);
  u32 hi = (u32)f2b(dv.z * inv * wv.z + bv.z) |
           ((u32)f2b(dv.w * inv * wv.w + bv.w) << 16);
  ((uint2*)(o + (long)row * 256))[lane] = make_uint2(lo, hi);
}

// ---- softmax rows of 1024: f32 in, bf16 out (wave per row) ----------------
__global__ __launch_bounds__(256) void softmax_k(const float* __restrict__ S,
                                                 u16* __restrict__ P) {
  int row = blockIdx.x * 4 + (threadIdx.x >> 6);
  int lane = threadIdx.x & 63;
  const float4* p = (const float4*)(S + (long)row * 1024);
  float4 v[4];
  float m = -1e30f;
  #pragma unroll
  for (int i = 0; i < 4; ++i) {
    v[i] = p[lane * 4 + i];
    m = fmaxf(m, fmaxf(fmaxf(v[i].x, v[i].y), fmaxf(v[i].z, v[i].w)));
  }
  #pragma unroll
  for (int q = 32; q; q >>= 1) m = fmaxf(m, __shfl_xor(m, q));
  float s = 0.f;
  #pragma unroll
  for (int i = 0; i < 4; ++i) {
    v[i].x = expf(v[i].x - m); v[i].y = expf(v[i].y - m);
    v[i].z = expf(v[i].z - m); v[i].w = expf(v[i].w - m);
    s += v[i].x + v[i].y + v[i].z + v[i].w;
  }
  #pragma unroll
  for (int q = 32; q; q >>= 1) s += __shfl_xor(s, q);
  float inv = 1.f / s;
  uint2* q2 = (uint2*)(P + (long)row * 1024);
  #pragma unroll
  for (int i = 0; i < 4; ++i) {
    u32 lo = (u32)f2b(v[i].x * inv) | ((u32)f2b(v[i].y * inv) << 16);
    u32 hi = (u32)f2b(v[i].z * inv) | ((u32)f2b(v[i].w * inv) << 16);
    q2[lane * 4 + i] = make_uint2(lo, hi);
  }
}

// ---- bf16 MFMA GEMM: Out = act(alpha * A @ B^T + bias) --------------------
// act: 0 none, 1 relu, 4 fused BC/dt epilogue (Out2=XDBL f32, OutF=DU, Aux=XMC)
__global__ __launch_bounds__(256, 2) void bgemm_k(
    const u16* __restrict__ A, const u16* __restrict__ B,
    const float* __restrict__ bias, float* __restrict__ OutF,
    u16* __restrict__ OutH, int M, int N, int K,
    int lda, int ldb, int ldo, int zdiv,
    long a_zb, long a_zh, long b_zb, long b_zh, long o_zb, long o_zh,
    float alpha, int act, int bias_zb, float* __restrict__ Out2,
    const float* __restrict__ Aux) {
  __shared__ u16 ldsA[4][128][8];
  __shared__ u16 ldsB[4][128][8];
  int z = blockIdx.z, zb = z / zdiv, zh = z - zb * zdiv;
  const u16* Ab = A + zb * a_zb + zh * a_zh;
  const u16* Bb = B + zb * b_zb + zh * b_zh;
  const float* biasb = bias ? bias + (long)zb * bias_zb : nullptr;
  long ob = zb * o_zb + zh * o_zh;
  int m0 = blockIdx.x * 128, n0 = blockIdx.y * 128;
  int tid = threadIdx.x;
  int lane = tid & 63, wv = tid >> 6;
  int wr = wv >> 1, wc = wv & 1;
  int r1 = tid & 127, h1 = tid >> 7;
  int r2 = r1, h2 = h1 + 2;
  const u16* a1 = Ab + (long)(m0 + r1) * lda + h1 * 8;
  const u16* a2 = Ab + (long)(m0 + r2) * lda + h2 * 8;
  const u16* b1 = Bb + (long)(n0 + r1) * ldb + h1 * 8;
  const u16* b2 = Bb + (long)(n0 + r2) * ldb + h2 * 8;

  f32x4 acc[4][4];
  #pragma unroll
  for (int i = 0; i < 4; ++i)
    #pragma unroll
    for (int j = 0; j < 4; ++j) acc[i][j] = (f32x4){0.f, 0.f, 0.f, 0.f};

  bf16x8 ra1 = *(const bf16x8*)a1;
  bf16x8 ra2 = *(const bf16x8*)a2;
  bf16x8 rb1 = *(const bf16x8*)b1;
  bf16x8 rb2 = *(const bf16x8*)b2;

  int nt = K >> 5;
  int kh = lane >> 4, rlo = lane & 15;
  for (int t = 0; t < nt; ++t) {
    __syncthreads();
    *(bf16x8*)&ldsA[h1][r1][0] = ra1;
    *(bf16x8*)&ldsA[h2][r2][0] = ra2;
    *(bf16x8*)&ldsB[h1][r1][0] = rb1;
    *(bf16x8*)&ldsB[h2][r2][0] = rb2;
    if (t + 1 < nt) {
      int ko = (t + 1) << 5;
      ra1 = *(const bf16x8*)(a1 + ko);
      ra2 = *(const bf16x8*)(a2 + ko);
      rb1 = *(const bf16x8*)(b1 + ko);
      rb2 = *(const bf16x8*)(b2 + ko);
    }
    __syncthreads();
    bf16x8 af[4], bfr[4];
    #pragma unroll
    for (int m = 0; m < 4; ++m)
      af[m] = *(const bf16x8*)&ldsA[kh][wr * 64 + m * 16 + rlo][0];
    #pragma unroll
    for (int n = 0; n < 4; ++n)
      bfr[n] = *(const bf16x8*)&ldsB[kh][wc * 64 + n * 16 + rlo][0];
    #pragma unroll
    for (int m = 0; m < 4; ++m)
      #pragma unroll
      for (int n = 0; n < 4; ++n)
        acc[m][n] = __builtin_amdgcn_mfma_f32_16x16x32_bf16(af[m], bfr[n],
                                                            acc[m][n], 0, 0, 0);
  }
  int rowb = (lane >> 4) * 4;
  #pragma unroll
  for (int m = 0; m < 4; ++m) {
    #pragma unroll
    for (int n = 0; n < 4; ++n) {
      int gn = n0 + wc * 64 + n * 16 + rlo;
      float bv = biasb ? biasb[gn] : 0.f;
      #pragma unroll
      for (int j = 0; j < 4; ++j) {
        int gm = m0 + wr * 64 + m * 16 + rowb + j;
        float v = acc[m][n][j] * alpha + bv;
        if (act == 4) {
          if (gn < 32) {
            Out2[(long)(zb * 4096 + gm) * 32 + gn] = v;
          } else if (gn < 544) {
            float sp = (v > 30.f) ? v : log1pf(expf(v));
            long di = (long)(zb * 4096 + gm) * 512 + (gn - 32);
            ((float2*)OutF)[di] = make_float2(sp, Aux[di]);
          }
        } else {
          if (act == 1) v = fmaxf(v, 0.f);
          long oi = ob + (long)gm * ldo + gn;
          if (OutH) OutH[oi] = f2b(v);
          else OutF[oi] = v;
        }
      }
    }
  }
}

// ---- V transpose ----------------------------------------------------------
__global__ __launch_bounds__(256) void vt_k(const u16* __restrict__ qkv,
                                            u16* __restrict__ vt) {
  int t = blockIdx.x * 256 + threadIdx.x;    // < 1,048,576
  int j = t & 1023, d = (t >> 10) & 127, bh = t >> 17;
  int b = bh >> 1, h = bh & 1;
  vt[t] = qkv[((long)(b * 1024 + j)) * 768 + 512 + h * 128 + d];
}

// ---- x_att permute --------------------------------------------------------
__global__ __launch_bounds__(256) void xatt_k(const float* __restrict__ hs,
                                              u16* __restrict__ xa) {
  int t = blockIdx.x * 256 + threadIdx.x;    // < 1,048,576
  int dm = t & 255, l = (t >> 8) & 1023, b = t >> 18;
  xa[t] = f2b(hs[((long)b << 18) + dm * 1024 + l]);
}

// ---- branch sequence index map --------------------------------------------
__device__ __forceinline__ int brmap(int br, int j) {
  if (br == 0) return j;
  if (br == 1) return 1023 - j;
  return ((j & 15) << 6) | (j >> 4);
}

// ---- causal conv1d (k=4) + silu; writes f32 + bf16 + silu(z) bf16 ---------
__global__ __launch_bounds__(256) void cconv_k(const u16* __restrict__ xzb,
                                               const float* __restrict__ pk,
                                               float* __restrict__ xmc,
                                               u16* __restrict__ xmcb,
                                               u16* __restrict__ zs) {
  long t = (long)blockIdx.x * 256 + threadIdx.x;   // < 6,291,456
  int d = (int)(t & 511);
  long r = t >> 9;
  int j = (int)(r & 1023);
  int bb = (int)(r >> 10);
  int b = bb & 3, br = bb >> 2;
  const float* pb = pk + (long)br * BRS;
  float acc = pb[2048 + d];
  #pragma unroll
  for (int tap = 0; tap < 4; ++tap) {
    int jj = j - 3 + tap;
    if (jj >= 0) {
      int l = brmap(br, jj);
      acc = fmaf(b2f(xzb[(((long)b << 10) + l) * 1024 + d]), pb[d * 4 + tap],
                 acc);
    }
  }
  float sig = 1.f / (1.f + expf(-acc));
  float u = acc * sig;
  xmc[t] = u;
  xmcb[t] = f2b(u);
  int l = brmap(br, j);
  float zv = b2f(xzb[(((long)b << 10) + l) * 1024 + 512 + d]);
  zs[t] = f2b(zv / (1.f + expf(-zv)));
}

// ---- chunked selective scan, 4 lanes/row x 4 states/lane ------------------
__global__ __launch_bounds__(256) void scanA_k(
    const float2* __restrict__ du, const float* __restrict__ xdbl,
    const float* __restrict__ pk, float* __restrict__ SE,
    float* __restrict__ PC) {
  __shared__ float bs[LCH][16];
  int tid = threadIdx.x;
  int wv = tid >> 6, lane = tid & 63;
  int q = lane & 3, dl = lane >> 2;
  int bb = blockIdx.x >> 3, dch = blockIdx.x & 7;
  int br = bb >> 2, b = bb & 3;
  int d = dch * 64 + wv * 16 + dl;
  int c = blockIdx.y;
  long xdb = (long)br * 131072 + (long)b * 32768 + (long)(c * LCH) * 32;
  {
    int j = tid >> 2, g = tid & 3;   // LCH*4 = 256 float4s
    *(float4*)&bs[j][g * 4] = *(const float4*)&xdbl[xdb + j * 32 + g * 4];
  }
  __syncthreads();
  const float* pb = pk + (long)br * BRS;
  float4 Aln = *(const float4*)&pb[35840 + d * 16 + q * 4];
  long obase = ((long)bb << 19) + (long)(c * LCH) * 512 + d;
  const float2* pdu = du + obase;
  float4 s = {0.f, 0.f, 0.f, 0.f};
  float S = 0.f;
  #pragma unroll 4
  for (int jl = 0; jl < LCH; ++jl) {
    float2 dv = pdu[(long)jl * 512];
    float w = dv.x * dv.y;
    float4 Bv = *(const float4*)&bs[jl][q * 4];
    s.x = fmaf(exp2f(dv.x * Aln.x), s.x, w * Bv.x);
    s.y = fmaf(exp2f(dv.x * Aln.y), s.y, w * Bv.y);
    s.z = fmaf(exp2f(dv.x * Aln.z), s.z, w * Bv.z);
    s.w = fmaf(exp2f(dv.x * Aln.w), s.w, w * Bv.w);
    S += dv.x;
  }
  long si = ((((long)bb) * NCH + c) * 512 + d) * 16 + q * 4;
  *(float4*)&SE[si] = s;
  float4 P = {exp2f(Aln.x * S), exp2f(Aln.y * S),
              exp2f(Aln.z * S), exp2f(Aln.w * S)};
  *(float4*)&PC[si] = P;
}

__global__ __launch_bounds__(256) void scanB_k(const float* __restrict__ SE,
                                               const float* __restrict__ PC,
                                               float* __restrict__ SI) {
  long t = (long)blockIdx.x * 256 + threadIdx.x;   // < 98,304
  int n = (int)(t & 15);
  int d = (int)((t >> 4) & 511);
  int bb = (int)(t >> 13);
  float run = 0.f;
  for (int c = 0; c < NCH; ++c) {
    long si = (((long)bb * NCH + c) * 512 + d) * 16 + n;
    SI[si] = run;
    run = fmaf(PC[si], run, SE[si]);
  }
}

__global__ __launch_bounds__(256) void scanC_k(
    const float2* __restrict__ du, const float* __restrict__ xdbl,
    const u16* __restrict__ zs, const float* __restrict__ pk,
    const float* __restrict__ SI, u16* __restrict__ y) {
  __shared__ float bcs[LCH][32];
  int tid = threadIdx.x;
  int wv = tid >> 6, lane = tid & 63;
  int q = lane & 3, dl = lane >> 2;
  int bb = blockIdx.x >> 3, dch = blockIdx.x & 7;
  int br = bb >> 2, b = bb & 3;
  int d = dch * 64 + wv * 16 + dl;
  int c = blockIdx.y;
  long xdb = (long)br * 131072 + (long)b * 32768 + (long)(c * LCH) * 32;
  #pragma unroll
  for (int i = 0; i < 2; ++i) {
    int idx = tid + i * 256;                 // LCH*8 = 512 float4s
    int j = idx >> 3, g = idx & 7;
    *(float4*)&bcs[j][g * 4] = *(const float4*)&xdbl[xdb + j * 32 + g * 4];
  }
  __syncthreads();
  const float* pb = pk + (long)br * BRS;
  float4 Aln = *(const float4*)&pb[35840 + d * 16 + q * 4];
  float Dv = pb[44032 + d];
  long obase = ((long)bb << 19) + (long)(c * LCH) * 512 + d;
  long si = ((((long)bb) * NCH + c) * 512 + d) * 16 + q * 4;
  float4 s = *(const float4*)&SI[si];
  const float2* pdu = du + obase;
  const u16* pzs = zs + obase;
  u16* py = y + obase;
  #pragma unroll 4
  for (int jl = 0; jl < LCH; ++jl) {
    float2 dv = pdu[(long)jl * 512];
    float w = dv.x * dv.y;
    float4 Bv = *(const float4*)&bcs[jl][q * 4];
    float4 Cv = *(const float4*)&bcs[jl][16 + q * 4];
    s.x = fmaf(exp2f(dv.x * Aln.x), s.x, w * Bv.x);
    s.y = fmaf(exp2f(dv.x * Aln.y), s.y, w * Bv.y);
    s.z = fmaf(exp2f(dv.x * Aln.z), s.z, w * Bv.z);
    s.w = fmaf(exp2f(dv.x * Aln.w), s.w, w * Bv.w);
    float p = s.x * Cv.x;
    p = fmaf(s.y, Cv.y, p);
    p = fmaf(s.z, Cv.z, p);
    p = fmaf(s.w, Cv.w, p);
    DPP_ADD(p, 0xB1);    // + lane^1
    DPP_ADD(p, 0x4E);    // + lane^2
    if (q == 0)
      py[(long)jl * 512] = f2b((p + Dv * dv.y) * b2f(pzs[(long)jl * 512]));
  }
}

// ---- combine 3 branch outputs -> COMBB bf16 (b,l,512) ---------------------
__global__ __launch_bounds__(256) void combine_k(const u16* __restrict__ y,
                                                 u16* __restrict__ comb) {
  long t = (long)blockIdx.x * 256 + threadIdx.x;   // < 2,097,152
  int d = (int)(t & 511);
  long r = t >> 9;
  int l = (int)(r & 1023);
  int b = (int)(r >> 10);
  int j2 = ((l & 63) << 4) | (l >> 6);
  float v = b2f(y[(((long)b << 10) + l) * 512 + d])
          + b2f(y[(((long)(4 + b) << 10) + (1023 - l)) * 512 + d])
          + b2f(y[(((long)(8 + b) << 10) + j2) * 512 + d]);
  comb[t] = f2b(v);
}

// ---- depthwise 3x3 conv + residual add, NCHW output -----------------------
// grid 1024 = (b,c); channel plane staged in LDS; coalesced stores.
__global__ __launch_bounds__(256) void dw_k(const u16* __restrict__ xfb,
                                            const float* __restrict__ dww,
                                            const float* __restrict__ dwb,
                                            const float* __restrict__ x,
                                            float* __restrict__ out) {
  __shared__ float plane[1024];
  int bc = blockIdx.x;
  int b = bc >> 8, c = bc & 255;
  int tid = threadIdx.x;
  #pragma unroll
  for (int i = 0; i < 4; ++i) {
    int n = tid + i * 256;
    plane[n] = b2f(xfb[(((long)b << 10) + n) * 256 + c]);
  }
  __syncthreads();
  float wv[9];
  #pragma unroll
  for (int k = 0; k < 9; ++k) wv[k] = dww[c * 9 + k];
  float bb = dwb[c];
  long obase = ((long)(b * 256 + c)) << 10;
  #pragma unroll
  for (int i = 0; i < 4; ++i) {
    int n = tid + i * 256;
    int h = n >> 5, w = n & 31;
    float acc = bb;
    #pragma unroll
    for (int kh = 0; kh < 3; ++kh) {
      int hh = h + kh - 1;
      if ((unsigned)hh >= 32u) continue;
      #pragma unroll
      for (int kw = 0; kw < 3; ++kw) {
        int ww = w + kw - 1;
        if ((unsigned)ww >= 32u) continue;
        acc = fmaf(plane[hh * 32 + ww], wv[kh * 3 + kw], acc);
      }
    }
    out[obase + n] = acc + x[obase + n];
  }
}

// ---------------------------------------------------------------------------
extern "C" void kernel_launch(void* const* d_in, const int* in_sizes, int n_in,
                              void* d_out, int out_size, void* d_ws, size_t ws_size,
                              hipStream_t stream) {
  (void)in_sizes; (void)n_in; (void)out_size; (void)ws_size;
  const float* x    = (const float*)d_in[0];
  const float* p1w  = (const float*)d_in[1];
  const float* p1b  = (const float*)d_in[2];
  const float* p2w  = (const float*)d_in[3];
  const float* p2b  = (const float*)d_in[4];
  const float* nw   = (const float*)d_in[5];
  const float* nb   = (const float*)d_in[6];
  const float* qw   = (const float*)d_in[7];
  const float* qb   = (const float*)d_in[8];
  const float* kw   = (const float*)d_in[9];
  const float* kb   = (const float*)d_in[10];
  const float* vw   = (const float*)d_in[11];
  const float* vb   = (const float*)d_in[12];
  const float* ow   = (const float*)d_in[13];
  const float* ob   = (const float*)d_in[14];
  const float* fc1w = (const float*)d_in[15];
  const float* fc1b = (const float*)d_in[16];
  const float* dww  = (const float*)d_in[17];
  const float* dwb  = (const float*)d_in[18];
  const float* inw  = (const float*)d_in[19];
  const float* cw   = (const float*)d_in[20];
  const float* cb   = (const float*)d_in[21];
  const float* cbw  = (const float*)d_in[22];
  const float* cbb  = (const float*)d_in[23];
  const float* csw  = (const float*)d_in[24];
  const float* csb  = (const float*)d_in[25];
  const float* xpw  = (const float*)d_in[26];
  const float* xpbw = (const float*)d_in[27];
  const float* xpsw = (const float*)d_in[28];
  const float* dtw  = (const float*)d_in[29];
  const float* dtb  = (const float*)d_in[30];
  const float* dtbw = (const float*)d_in[31];
  const float* dtbb = (const float*)d_in[32];
  const float* dtsw = (const float*)d_in[33];
  const float* dtsb = (const float*)d_in[34];
  const float* Alog = (const float*)d_in[35];
  const float* Ablog= (const float*)d_in[36];
  const float* Aslog= (const float*)d_in[37];
  const float* Dv   = (const float*)d_in[38];
  const float* Dbv  = (const float*)d_in[39];
  const float* Dsv  = (const float*)d_in[40];
  const float* outw = (const float*)d_in[41];
  float* out = (float*)d_out;

  float* ws    = (float*)d_ws;
  float* PB    = ws;                          // 133,632
  u16*   WCONV = (u16*)(ws + 140000);         // 294,912 u16
  u16*   WB    = (u16*)(ws + 440000);         // 786,432 u16
  float* QBIAS = ws + 840000;                 // 768
  u16*   XINB  = (u16*)(ws + 850000);         // 1,048,576 u16
  float* R     = ws + 1400000;

  // mamba/scan phase
  u16*    XZB  = (u16*)R;                     // 4.2M f32-eq; dead after cconv
  float2* DU   = (float2*)R;                  // 12.58M f32; fused-gemm output
  u16*    ZS   = (u16*)(R + 12600000);        // 3.15M f32-eq
  float*  XMC  = R + 15750000;                // 6.3M; dead after fused ->
  float*  SE   = R + 15750000;
  float*  PC   = R + 17350000;
  float*  SI   = R + 19000000;
  u16*    Y    = (u16*)(R + 20600000);        // 3.15M f32-eq
  u16*    XMCB = (u16*)(R + 22050000);        // 3.15M f32-eq; dead after fused
  u16*   COMBB = (u16*)(R + 23750000);
  float*  XDBL = R + 25200000;                // [3][4096][32]
  u16*    WMB  = (u16*)(R + 25600000);        // [3][640][512] bf16
  float*  BIA  = R + 26100000;                // [3][640]
  // attn phase (dead before mamba)
  float* XCT   = R + 4300000;
  u16*   XCTB  = (u16*)(R + 5400000);
  u16*   QKVB  = (u16*)(R + 6000000);
  u16*   VT    = (u16*)(R + 7600000);
  float* SC    = R + 8200000;
  u16*   P     = (u16*)(R + 16600000);
  u16*   ATTB  = (u16*)(R + 20900000);
  float* HS    = R + 21500000;
  u16*   XATTB = (u16*)(R + 22600000);
  // tail phase
  u16*   XMBB  = (u16*)R;
  u16*   XM2B  = (u16*)(R + 600000);
  u16*   XPB   = (u16*)(R + 1200000);
  u16*   XFB   = (u16*)(R + 1800000);

  u16* WQKVB = WB;
  u16* OWB   = WB + 196608;
  u16* INWB  = WB + 262144;
  u16* OUTWB = WB + 524288;
  u16* P2WB  = WB + 655360;
  u16* FC1WB = WB + 720896;

  auto bgemm = [&](const u16* A, const u16* Bm, const float* bias,
                   float* OutF, u16* OutH, int M, int N, int K,
                   int lda, int ldb, int ldo, int nz, int zdiv,
                   long a_zb, long a_zh, long b_zb, long b_zh,
                   long o_zb, long o_zh, float alpha, int act,
                   int bias_zb, float* Out2, const float* Aux) {
    dim3 g(M / 128, N / 128, nz);
    bgemm_k<<<g, 256, 0, stream>>>(A, Bm, bias, OutF, OutH, M, N, K,
                                   lda, ldb, ldo, zdiv, a_zb, a_zh,
                                   b_zb, b_zh, o_zb, o_zh, alpha, act,
                                   bias_zb, Out2, Aux);
  };

  // 0) pack params
  BrP b0 = {cw, cb, xpw, dtw, dtb, Alog, Dv};
  BrP b1 = {cbw, cbb, xpbw, dtbw, dtbb, Ablog, Dbv};
  BrP b2 = {csw, csb, xpsw, dtsw, dtsb, Aslog, Dsv};
  pack_branch_k<<<dim3(174, 3), 256, 0, stream>>>(PB, b0, b1, b2);
  pack_wb_k<<<3075, 256, 0, stream>>>(qw, kw, vw, ow, inw, outw, p2w, fc1w,
                                      qb, kb, vb, WB, QBIAS);
  pack_wc_k<<<2304, 256, 0, stream>>>(p1w, WCONV);
  xin_k<<<4096, 256, 0, stream>>>(x, XINB);
  pack_wmb_k<<<dim3(259, 3), 256, 0, stream>>>(PB, WMB, BIA);
  pack_wdt_k<<<dim3(512, 3), 256, 0, stream>>>(PB, WMB);

  // 1) conv1 (MFMA) -> XCT f32; LN -> XCTB bf16
  conv_mfma_k<<<dim3(64, 4), 256, 0, stream>>>(XINB, WCONV, p1b, XCT, nullptr, 0);
  layernorm_k<<<1024, 256, 0, stream>>>(XCT, nw, nb, XCTB);

  // 2) fused QKV -> QKVB bf16 [4096][768]
  bgemm(XCTB, WQKVB, QBIAS, nullptr, QKVB, 4096, 768, 256, 256, 256, 768,
        1, 1, 0, 0, 0, 0, 0, 0, 1.f, 0, 0, nullptr, nullptr);
  vt_k<<<4096, 256, 0, stream>>>(QKVB, VT);

  // 3) scores f32 = QK^T/sqrt(128); softmax -> P bf16
  bgemm(QKVB, QKVB + 256, nullptr, SC, nullptr, 1024, 1024, 128, 768, 768, 1024,
        8, 2, 786432, 128, 786432, 128, 2097152, 1048576,
        0.08838834764831845f, 0, 0, nullptr, nullptr);
  softmax_k<<<2048, 256, 0, stream>>>(SC, P);

  // 4) att = P @ V^T -> ATTB bf16 [4096][256]
  bgemm(P, VT, nullptr, nullptr, ATTB, 1024, 128, 1024, 1024, 1024, 256,
        8, 2, 2097152, 1048576, 262144, 131072, 262144, 128, 1.f, 0,
        0, nullptr, nullptr);

  // 5) o-projection -> HS f32; permute -> XATTB bf16
  bgemm(ATTB, OWB, ob, HS, nullptr, 4096, 256, 256, 256, 256, 256,
        1, 1, 0, 0, 0, 0, 0, 0, 1.f, 0, 0, nullptr, nullptr);
  xatt_k<<<4096, 256, 0, stream>>>(HS, XATTB);

  // 6) xz = x_att @ in_w^T -> XZB bf16 [4][1024][1024]
  bgemm(XATTB, INWB, nullptr, nullptr, XZB, 1024, 1024, 256, 256, 256, 1024,
        4, 1, 262144, 0, 0, 0, 1048576, 0, 1.f, 0, 0, nullptr, nullptr);

  // 7) causal conv1d + silu -> XMC f32 + XMCB bf16; silu(z) -> ZS bf16
  cconv_k<<<24576, 256, 0, stream>>>(XZB, PB, XMC, XMCB, ZS);

  // 8+9) fused B/C + dt GEMM -> XDBL f32 [3][4096][32] + DU float2
  bgemm(XMCB, WMB, BIA, (float*)DU, nullptr, 4096, 640, 512, 512, 512, 0,
        3, 1, 2097152, 0, 327680, 0, 0, 0, 1.f, 4, 640, XDBL, XMC);

  // 10) chunked selective scan -> Y bf16
  scanA_k<<<dim3(96, NCH), 256, 0, stream>>>(DU, XDBL, PB, SE, PC);
  scanB_k<<<384, 256, 0, stream>>>(SE, PC, SI);
  scanC_k<<<dim3(96, NCH), 256, 0, stream>>>(DU, XDBL, ZS, PB, SI, Y);

  // 11) combine -> COMBB bf16
  combine_k<<<8192, 256, 0, stream>>>(Y, COMBB);

  // 12) mamba out projection -> XMBB bf16
  bgemm(COMBB, OUTWB, nullptr, nullptr, XMBB, 4096, 256, 512, 512, 512, 256,
        1, 1, 0, 0, 0, 0, 0, 0, 1.f, 0, 0, nullptr, nullptr);

  // 13) conv1 again (MFMA, NHWC bf16) + relu -> XM2B bf16
  conv_mfma_k<<<dim3(64, 4), 256, 0, stream>>>(XMBB, WCONV, p1b, nullptr, XM2B, 1);

  // 14) proj2 + relu -> XPB bf16
  bgemm(XM2B, P2WB, p2b, nullptr, XPB, 4096, 256, 256, 256, 256, 256,
        1, 1, 0, 0, 0, 0, 0, 0, 1.f, 1, 0, nullptr, nullptr);

  // 15) fc1 -> XFB bf16
  bgemm(XPB, FC1WB, fc1b, nullptr, XFB, 4096, 256, 256, 256, 256, 256,
        1, 1, 0, 0, 0, 0, 0, 0, 1.f, 0, 0, nullptr, nullptr);

  // 16) depthwise 3x3 + residual -> out
  dw_k<<<1024, 256, 0, stream>>>(XFB, dww, dwb, x, out);
}

// Round 9
// 597.807 us; speedup vs baseline: 1.1241x; 1.1241x over previous
//
#include <hip/hip_runtime.h>

// ---------------------------------------------------------------------------
// Att_MambaLayer: bf16-MFMA everywhere + fused BC/dt GEMM (bf16-packed DU)
// + chunked selective scan. B=4, C=256, H=W=32, l=1024, DI=512, DS=16.
// ---------------------------------------------------------------------------

#define LOG2E 1.4426950408889634f
#define NCH 16
#define LCH 64

typedef unsigned short u16;
typedef unsigned int u32;
typedef __attribute__((ext_vector_type(8))) short bf16x8;
typedef __attribute__((ext_vector_type(4))) float f32x4;

__device__ __forceinline__ u16 f2b(float f) {
  u32 u = __builtin_bit_cast(u32, f);
  u32 r = (u + 0x7fffu + ((u >> 16) & 1u)) >> 16;
  return (u16)r;
}
__device__ __forceinline__ float b2f(u16 h) {
  u32 u = ((u32)h) << 16;
  return __builtin_bit_cast(float, u);
}

#define DPP_ADD(p, ctrl)                                                   \
  (p) += __builtin_bit_cast(float, __builtin_amdgcn_update_dpp(            \
             0, __builtin_bit_cast(int, (p)), ctrl, 0xF, 0xF, true))

static const long BRS = 44544;

// ---- param packing --------------------------------------------------------
struct BrP { const float *cw, *cb, *xpw, *dtw, *dtb, *Al, *Dv; };

__global__ __launch_bounds__(256) void pack_branch_k(float* __restrict__ dst0,
                                                     BrP p0, BrP p1, BrP p2) {
  int z = blockIdx.y;
  BrP p = (z == 0) ? p0 : ((z == 1) ? p1 : p2);
  float* dst = dst0 + (long)z * BRS;
  int t = blockIdx.x * 256 + threadIdx.x;
  if (t < 2048) dst[t] = p.cw[t];
  else if (t < 2560) dst[t] = p.cb[t - 2048];
  else if (t < 27136) dst[t] = p.xpw[t - 2560];
  else if (t < 35328) dst[t] = p.dtw[t - 27136];
  else if (t < 35840) dst[t] = p.dtb[t - 35328];
  else if (t < 44032) dst[t] = -expf(p.Al[t - 35840]) * LOG2E;
  else if (t < 44544) dst[t] = p.Dv[t - 44032];
}

__global__ __launch_bounds__(256) void pack_wb_k(
    const float* __restrict__ qw, const float* __restrict__ kw,
    const float* __restrict__ vw, const float* __restrict__ ow,
    const float* __restrict__ inw, const float* __restrict__ outw,
    const float* __restrict__ p2w, const float* __restrict__ fc1w,
    const float* __restrict__ qb, const float* __restrict__ kb,
    const float* __restrict__ vb, u16* __restrict__ WB,
    float* __restrict__ QBIAS) {
  int t = blockIdx.x * 256 + threadIdx.x;   // < 787,200
  if (t < 65536) WB[t] = f2b(qw[t]);
  else if (t < 131072) WB[t] = f2b(kw[t - 65536]);
  else if (t < 196608) WB[t] = f2b(vw[t - 131072]);
  else if (t < 262144) WB[t] = f2b(ow[t - 196608]);
  else if (t < 524288) WB[t] = f2b(inw[t - 262144]);
  else if (t < 655360) WB[t] = f2b(outw[t - 524288]);
  else if (t < 720896) WB[t] = f2b(p2w[t - 655360]);
  else if (t < 786432) WB[t] = f2b(fc1w[t - 720896]);
  else if (t < 787200) {
    int i = t - 786432;
    QBIAS[i] = (i < 256) ? qb[i] : (i < 512 ? kb[i - 256] : vb[i - 512]);
  }
}

// conv weight pack: wc[co][(kh*3+kw)*256+ci] = w[co][ci][kh][kw]
__global__ __launch_bounds__(256) void pack_wc_k(const float* __restrict__ w,
                                                 u16* __restrict__ wc) {
  int t = blockIdx.x * 256 + threadIdx.x;   // < 589,824
  int ci = t & 255, khw = (t >> 8) % 9, co = t / 2304;
  wc[t] = f2b(w[co * 2304 + ci * 9 + khw]);
}

// x input -> shuffled NHWC bf16 (the x_flat permutation)
__global__ __launch_bounds__(256) void xin_k(const float* __restrict__ x,
                                             u16* __restrict__ xin) {
  int t = blockIdx.x * 256 + threadIdx.x;   // < 1,048,576
  int ci = t & 255, w = (t >> 8) & 31, h = (t >> 13) & 31, b = t >> 18;
  int idx = ci * 32 + h;
  xin[t] = f2b(x[((long)b << 18) + ((long)(idx & 255) << 10) +
                 ((idx >> 8) << 5) + w]);
}

// WMB rows 0..31 (B,C from xpw rows 16..47), rows 544..639 zero, bias vector
__global__ __launch_bounds__(256) void pack_wmb_k(const float* __restrict__ PB,
                                                  u16* __restrict__ WMB,
                                                  float* __restrict__ BIA) {
  int z = blockIdx.y;
  int t = blockIdx.x * 256 + threadIdx.x;   // < 66,176
  const float* pb = PB + (long)z * BRS;
  if (t < 16384) {
    int r = t >> 9, k = t & 511;
    WMB[((long)z * 640 + r) * 512 + k] = f2b(pb[2560 + (16 + r) * 512 + k]);
  } else if (t < 65536) {
    int i = t - 16384;
    int r = 544 + (i >> 9), k = i & 511;
    WMB[((long)z * 640 + r) * 512 + k] = 0;
  } else if (t < 66176) {
    int i = t - 65536;   // 0..639
    float v = 0.f;
    if (i >= 32 && i < 544) v = pb[35328 + (i - 32)];
    BIA[(long)z * 640 + i] = v;
  }
}

// W_dt = dtw @ xpw[:16]  -> WMB rows 32..543
__global__ __launch_bounds__(256) void pack_wdt_k(const float* __restrict__ PB,
                                                  u16* __restrict__ WMB) {
  int z = blockIdx.y, d = blockIdx.x;
  const float* pb = PB + (long)z * BRS;
  float dtwv[16];
  #pragma unroll
  for (int r = 0; r < 16; ++r) dtwv[r] = pb[27136 + d * 16 + r];
  #pragma unroll
  for (int i = 0; i < 2; ++i) {
    int k = threadIdx.x + i * 256;
    float acc = 0.f;
    #pragma unroll
    for (int r = 0; r < 16; ++r) acc = fmaf(dtwv[r], pb[2560 + r * 512 + k], acc);
    WMB[((long)z * 640 + 32 + d) * 512 + k] = f2b(acc);
  }
}

// ---- MFMA 3x3 conv --------------------------------------------------------
__global__ __launch_bounds__(256, 2) void conv_mfma_k(
    const u16* __restrict__ in, const u16* __restrict__ wc,
    const float* __restrict__ bias, float* __restrict__ outF,
    u16* __restrict__ outH, int relu) {
  __shared__ u16 ldsA[4][64][8];
  __shared__ u16 ldsB[4][64][8];
  int m0 = blockIdx.x * 64, n0 = blockIdx.y * 64;
  int tid = threadIdx.x;
  int lane = tid & 63, wv = tid >> 6;
  int row = tid & 63, k8 = tid >> 6;
  int l = m0 + row;
  int h = (l >> 5) & 31, w = l & 31;
  int rlo = lane & 15, khl = lane >> 4;
  f32x4 acc[4];
  #pragma unroll
  for (int n = 0; n < 4; ++n) acc[n] = (f32x4){0.f, 0.f, 0.f, 0.f};
  for (int t = 0; t < 72; ++t) {
    int kh = t / 24, r = t % 24, kw = r >> 3, ci0 = (r & 7) << 5;
    __syncthreads();
    bf16x8 av = (bf16x8){0, 0, 0, 0, 0, 0, 0, 0};
    int hh = h + kh - 1, ww = w + kw - 1;
    if ((unsigned)hh < 32u && (unsigned)ww < 32u)
      av = *(const bf16x8*)&in[(long)(l + (kh - 1) * 32 + (kw - 1)) * 256 +
                               ci0 + k8 * 8];
    *(bf16x8*)&ldsA[k8][row][0] = av;
    *(bf16x8*)&ldsB[k8][row][0] =
        *(const bf16x8*)&wc[(long)(n0 + row) * 2304 + t * 32 + k8 * 8];
    __syncthreads();
    bf16x8 af = *(const bf16x8*)&ldsA[khl][wv * 16 + rlo][0];
    #pragma unroll
    for (int n = 0; n < 4; ++n) {
      bf16x8 bf = *(const bf16x8*)&ldsB[khl][n * 16 + rlo][0];
      acc[n] = __builtin_amdgcn_mfma_f32_16x16x32_bf16(af, bf, acc[n], 0, 0, 0);
    }
  }
  int rowb = (lane >> 4) * 4;
  #pragma unroll
  for (int n = 0; n < 4; ++n) {
    int gn = n0 + n * 16 + rlo;
    float bv = bias[gn];
    #pragma unroll
    for (int j = 0; j < 4; ++j) {
      int gm = m0 + wv * 16 + rowb + j;
      float v = acc[n][j] + bv;
      if (relu) v = fmaxf(v, 0.f);
      long oi = (long)gm * 256 + gn;
      if (outH) outH[oi] = f2b(v);
      else outF[oi] = v;
    }
  }
}

// ---- LayerNorm rows of 256 -> bf16 (wave per row) -------------------------
__global__ __launch_bounds__(256) void layernorm_k(const float* __restrict__ x,
                                                   const float* __restrict__ w,
                                                   const float* __restrict__ b,
                                                   u16* __restrict__ o) {
  int row = blockIdx.x * 4 + (threadIdx.x >> 6);
  int lane = threadIdx.x & 63;
  float4 v = ((const float4*)(x + (long)row * 256))[lane];
  float s = v.x + v.y + v.z + v.w;
  #pragma unroll
  for (int m = 32; m; m >>= 1) s += __shfl_xor(s, m);
  float mean = s * (1.f / 256.f);
  float4 dv = {v.x - mean, v.y - mean, v.z - mean, v.w - mean};
  float vs = dv.x * dv.x + dv.y * dv.y + dv.z * dv.z + dv.w * dv.w;
  #pragma unroll
  for (int m = 32; m; m >>= 1) vs += __shfl_xor(vs, m);
  float inv = rsqrtf(vs * (1.f / 256.f) + 1e-5f);
  float4 wv = ((const float4*)w)[lane];
  float4 bv = ((const float4*)b)[lane];
  u32 lo = (u32)f2b(dv.x * inv * wv.x + bv.x) |
           ((u32)f2b(dv.y * inv * wv.y + bv.y) << 16);
  u32 hi = (u32)f2b(dv.z * inv * wv.z + bv.z) |
           ((u32)f2b(dv.w * inv * wv.w + bv.w) << 16);
  ((uint2*)(o + (long)row * 256))[lane] = make_uint2(lo, hi);
}

// ---- softmax rows of 1024: f32 in, bf16 out (wave per row) ----------------
__global__ __launch_bounds__(256) void softmax_k(const float* __restrict__ S,
                                                 u16* __restrict__ P) {
  int row = blockIdx.x * 4 + (threadIdx.x >> 6);
  int lane = threadIdx.x & 63;
  const float4* p = (const float4*)(S + (long)row * 1024);
  float4 v[4];
  float m = -1e30f;
  #pragma unroll
  for (int i = 0; i < 4; ++i) {
    v[i] = p[lane * 4 + i];
    m = fmaxf(m, fmaxf(fmaxf(v[i].x, v[i].y), fmaxf(v[i].z, v[i].w)));
  }
  #pragma unroll
  for (int q = 32; q; q >>= 1) m = fmaxf(m, __shfl_xor(m, q));
  float s = 0.f;
  #pragma unroll
  for (int i = 0; i < 4; ++i) {
    v[i].x = expf(v[i].x - m); v[i].y = expf(v[i].y - m);
    v[i].z = expf(v[i].z - m); v[i].w = expf(v[i].w - m);
    s += v[i].x + v[i].y + v[i].z + v[i].w;
  }
  #pragma unroll
  for (int q = 32; q; q >>= 1) s += __shfl_xor(s, q);
  float inv = 1.f / s;
  uint2* q2 = (uint2*)(P + (long)row * 1024);
  #pragma unroll
  for (int i = 0; i < 4; ++i) {
    u32 lo = (u32)f2b(v[i].x * inv) | ((u32)f2b(v[i].y * inv) << 16);
    u32 hi = (u32)f2b(v[i].z * inv) | ((u32)f2b(v[i].w * inv) << 16);
    q2[lane * 4 + i] = make_uint2(lo, hi);
  }
}

// ---- bf16 MFMA GEMM 128x128: Out = act(alpha * A @ B^T + bias) ------------
// act: 0 none, 1 relu, 4 fused BC/dt epilogue
//   (Out2=XDBL f32 cols<32; cols 32..543: softplus, pack bf16(delta)|bf16(u))
__global__ __launch_bounds__(256, 2) void bgemm_k(
    const u16* __restrict__ A, const u16* __restrict__ B,
    const float* __restrict__ bias, float* __restrict__ OutF,
    u16* __restrict__ OutH, int M, int N, int K,
    int lda, int ldb, int ldo, int zdiv,
    long a_zb, long a_zh, long b_zb, long b_zh, long o_zb, long o_zh,
    float alpha, int act, int bias_zb, float* __restrict__ Out2,
    const u16* __restrict__ Aux) {
  __shared__ u16 ldsA[4][128][8];
  __shared__ u16 ldsB[4][128][8];
  int z = blockIdx.z, zb = z / zdiv, zh = z - zb * zdiv;
  const u16* Ab = A + zb * a_zb + zh * a_zh;
  const u16* Bb = B + zb * b_zb + zh * b_zh;
  const float* biasb = bias ? bias + (long)zb * bias_zb : nullptr;
  long ob = zb * o_zb + zh * o_zh;
  int m0 = blockIdx.x * 128, n0 = blockIdx.y * 128;
  int tid = threadIdx.x;
  int lane = tid & 63, wv = tid >> 6;
  int wr = wv >> 1, wc = wv & 1;
  int r1 = tid & 127, h1 = tid >> 7;
  int r2 = r1, h2 = h1 + 2;
  const u16* a1 = Ab + (long)(m0 + r1) * lda + h1 * 8;
  const u16* a2 = Ab + (long)(m0 + r2) * lda + h2 * 8;
  const u16* b1 = Bb + (long)(n0 + r1) * ldb + h1 * 8;
  const u16* b2 = Bb + (long)(n0 + r2) * ldb + h2 * 8;

  f32x4 acc[4][4];
  #pragma unroll
  for (int i = 0; i < 4; ++i)
    #pragma unroll
    for (int j = 0; j < 4; ++j) acc[i][j] = (f32x4){0.f, 0.f, 0.f, 0.f};

  bf16x8 ra1 = *(const bf16x8*)a1;
  bf16x8 ra2 = *(const bf16x8*)a2;
  bf16x8 rb1 = *(const bf16x8*)b1;
  bf16x8 rb2 = *(const bf16x8*)b2;

  int nt = K >> 5;
  int kh = lane >> 4, rlo = lane & 15;
  for (int t = 0; t < nt; ++t) {
    __syncthreads();
    *(bf16x8*)&ldsA[h1][r1][0] = ra1;
    *(bf16x8*)&ldsA[h2][r2][0] = ra2;
    *(bf16x8*)&ldsB[h1][r1][0] = rb1;
    *(bf16x8*)&ldsB[h2][r2][0] = rb2;
    if (t + 1 < nt) {
      int ko = (t + 1) << 5;
      ra1 = *(const bf16x8*)(a1 + ko);
      ra2 = *(const bf16x8*)(a2 + ko);
      rb1 = *(const bf16x8*)(b1 + ko);
      rb2 = *(const bf16x8*)(b2 + ko);
    }
    __syncthreads();
    bf16x8 af[4], bfr[4];
    #pragma unroll
    for (int m = 0; m < 4; ++m)
      af[m] = *(const bf16x8*)&ldsA[kh][wr * 64 + m * 16 + rlo][0];
    #pragma unroll
    for (int n = 0; n < 4; ++n)
      bfr[n] = *(const bf16x8*)&ldsB[kh][wc * 64 + n * 16 + rlo][0];
    #pragma unroll
    for (int m = 0; m < 4; ++m)
      #pragma unroll
      for (int n = 0; n < 4; ++n)
        acc[m][n] = __builtin_amdgcn_mfma_f32_16x16x32_bf16(af[m], bfr[n],
                                                            acc[m][n], 0, 0, 0);
  }
  int rowb = (lane >> 4) * 4;
  #pragma unroll
  for (int m = 0; m < 4; ++m) {
    #pragma unroll
    for (int n = 0; n < 4; ++n) {
      int gn = n0 + wc * 64 + n * 16 + rlo;
      float bv = biasb ? biasb[gn] : 0.f;
      #pragma unroll
      for (int j = 0; j < 4; ++j) {
        int gm = m0 + wr * 64 + m * 16 + rowb + j;
        float v = acc[m][n][j] * alpha + bv;
        if (act == 4) {
          if (gn < 32) {
            Out2[(long)(zb * 4096 + gm) * 32 + gn] = v;
          } else if (gn < 544) {
            float sp = (v > 30.f) ? v : log1pf(expf(v));
            long di = (long)(zb * 4096 + gm) * 512 + (gn - 32);
            ((u32*)OutF)[di] = (u32)f2b(sp) | ((u32)Aux[di] << 16);
          }
        } else {
          if (act == 1) v = fmaxf(v, 0.f);
          long oi = ob + (long)gm * ldo + gn;
          if (OutH) OutH[oi] = f2b(v);
          else OutF[oi] = v;
        }
      }
    }
  }
}

// ---- bf16 MFMA GEMM 64x64 (for small-N / latency-bound GEMMs) -------------
__global__ __launch_bounds__(256, 2) void bgemm64_k(
    const u16* __restrict__ A, const u16* __restrict__ B,
    const float* __restrict__ bias, float* __restrict__ OutF,
    u16* __restrict__ OutH, int M, int N, int K,
    int lda, int ldb, int ldo, int zdiv,
    long a_zb, long a_zh, long b_zb, long b_zh, long o_zb, long o_zh,
    float alpha, int act) {
  __shared__ u16 ldsA[4][64][8];
  __shared__ u16 ldsB[4][64][8];
  int z = blockIdx.z, zb = z / zdiv, zh = z - zb * zdiv;
  const u16* Ab = A + zb * a_zb + zh * a_zh;
  const u16* Bb = B + zb * b_zb + zh * b_zh;
  long ob = zb * o_zb + zh * o_zh;
  int m0 = blockIdx.x * 64, n0 = blockIdx.y * 64;
  int tid = threadIdx.x;
  int lane = tid & 63, wv = tid >> 6;
  int row = tid & 63, k8 = tid >> 6;
  int rlo = lane & 15, khl = lane >> 4;
  const u16* pa = Ab + (long)(m0 + row) * lda + k8 * 8;
  const u16* pb = Bb + (long)(n0 + row) * ldb + k8 * 8;
  f32x4 acc[4];
  #pragma unroll
  for (int n = 0; n < 4; ++n) acc[n] = (f32x4){0.f, 0.f, 0.f, 0.f};
  bf16x8 ra = *(const bf16x8*)pa;
  bf16x8 rb = *(const bf16x8*)pb;
  int nt = K >> 5;
  for (int t = 0; t < nt; ++t) {
    __syncthreads();
    *(bf16x8*)&ldsA[k8][row][0] = ra;
    *(bf16x8*)&ldsB[k8][row][0] = rb;
    if (t + 1 < nt) {
      int ko = (t + 1) << 5;
      ra = *(const bf16x8*)(pa + ko);
      rb = *(const bf16x8*)(pb + ko);
    }
    __syncthreads();
    bf16x8 af = *(const bf16x8*)&ldsA[khl][wv * 16 + rlo][0];
    #pragma unroll
    for (int n = 0; n < 4; ++n) {
      bf16x8 bf = *(const bf16x8*)&ldsB[khl][n * 16 + rlo][0];
      acc[n] = __builtin_amdgcn_mfma_f32_16x16x32_bf16(af, bf, acc[n], 0, 0, 0);
    }
  }
  int rowb = (lane >> 4) * 4;
  #pragma unroll
  for (int n = 0; n < 4; ++n) {
    int gn = n0 + n * 16 + rlo;
    float bv = bias ? bias[gn] : 0.f;
    #pragma unroll
    for (int j = 0; j < 4; ++j) {
      int gm = m0 + wv * 16 + rowb + j;
      float v = acc[n][j] * alpha + bv;
      if (act == 1) v = fmaxf(v, 0.f);
      long oi = ob + (long)gm * ldo + gn;
      if (OutH) OutH[oi] = f2b(v);
      else OutF[oi] = v;
    }
  }
}

// ---- V transpose ----------------------------------------------------------
__global__ __launch_bounds__(256) void vt_k(const u16* __restrict__ qkv,
                                            u16* __restrict__ vt) {
  int t = blockIdx.x * 256 + threadIdx.x;    // < 1,048,576
  int j = t & 1023, d = (t >> 10) & 127, bh = t >> 17;
  int b = bh >> 1, h = bh & 1;
  vt[t] = qkv[((long)(b * 1024 + j)) * 768 + 512 + h * 128 + d];
}

// ---- x_att permute --------------------------------------------------------
__global__ __launch_bounds__(256) void xatt_k(const float* __restrict__ hs,
                                              u16* __restrict__ xa) {
  int t = blockIdx.x * 256 + threadIdx.x;    // < 1,048,576
  int dm = t & 255, l = (t >> 8) & 1023, b = t >> 18;
  xa[t] = f2b(hs[((long)b << 18) + dm * 1024 + l]);
}

// ---- branch sequence index map --------------------------------------------
__device__ __forceinline__ int brmap(int br, int j) {
  if (br == 0) return j;
  if (br == 1) return 1023 - j;
  return ((j & 15) << 6) | (j >> 4);
}

// ---- causal conv1d (k=4) + silu -> bf16; silu(z) -> bf16 ------------------
__global__ __launch_bounds__(256) void cconv_k(const u16* __restrict__ xzb,
                                               const float* __restrict__ pk,
                                               u16* __restrict__ xmcb,
                                               u16* __restrict__ zs) {
  long t = (long)blockIdx.x * 256 + threadIdx.x;   // < 6,291,456
  int d = (int)(t & 511);
  long r = t >> 9;
  int j = (int)(r & 1023);
  int bb = (int)(r >> 10);
  int b = bb & 3, br = bb >> 2;
  const float* pb = pk + (long)br * BRS;
  float acc = pb[2048 + d];
  #pragma unroll
  for (int tap = 0; tap < 4; ++tap) {
    int jj = j - 3 + tap;
    if (jj >= 0) {
      int l = brmap(br, jj);
      acc = fmaf(b2f(xzb[(((long)b << 10) + l) * 1024 + d]), pb[d * 4 + tap],
                 acc);
    }
  }
  float sig = 1.f / (1.f + expf(-acc));
  xmcb[t] = f2b(acc * sig);
  int l = brmap(br, j);
  float zv = b2f(xzb[(((long)b << 10) + l) * 1024 + 512 + d]);
  zs[t] = f2b(zv / (1.f + expf(-zv)));
}

// ---- chunked selective scan, 4 lanes/row x 4 states/lane ------------------
// DUB word: lo16 = bf16(delta), hi16 = bf16(u).
__global__ __launch_bounds__(256) void scanA_k(
    const u32* __restrict__ du, const float* __restrict__ xdbl,
    const float* __restrict__ pk, float* __restrict__ SE,
    float* __restrict__ PC) {
  __shared__ float bs[LCH][16];
  int tid = threadIdx.x;
  int wv = tid >> 6, lane = tid & 63;
  int q = lane & 3, dl = lane >> 2;
  int bb = blockIdx.x >> 3, dch = blockIdx.x & 7;
  int br = bb >> 2, b = bb & 3;
  int d = dch * 64 + wv * 16 + dl;
  int c = blockIdx.y;
  long xdb = (long)br * 131072 + (long)b * 32768 + (long)(c * LCH) * 32;
  {
    int j = tid >> 2, g = tid & 3;   // LCH*4 = 256 float4s
    *(float4*)&bs[j][g * 4] = *(const float4*)&xdbl[xdb + j * 32 + g * 4];
  }
  __syncthreads();
  const float* pb = pk + (long)br * BRS;
  float4 Aln = *(const float4*)&pb[35840 + d * 16 + q * 4];
  long obase = ((long)bb << 19) + (long)(c * LCH) * 512 + d;
  const u32* pdu = du + obase;
  float4 s = {0.f, 0.f, 0.f, 0.f};
  float S = 0.f;
  #pragma unroll 4
  for (int jl = 0; jl < LCH; ++jl) {
    u32 dv = pdu[(long)jl * 512];
    float delta = b2f((u16)dv);
    float uu = b2f((u16)(dv >> 16));
    float w = delta * uu;
    float4 Bv = *(const float4*)&bs[jl][q * 4];
    s.x = fmaf(exp2f(delta * Aln.x), s.x, w * Bv.x);
    s.y = fmaf(exp2f(delta * Aln.y), s.y, w * Bv.y);
    s.z = fmaf(exp2f(delta * Aln.z), s.z, w * Bv.z);
    s.w = fmaf(exp2f(delta * Aln.w), s.w, w * Bv.w);
    S += delta;
  }
  long si = ((((long)bb) * NCH + c) * 512 + d) * 16 + q * 4;
  *(float4*)&SE[si] = s;
  float4 P = {exp2f(Aln.x * S), exp2f(Aln.y * S),
              exp2f(Aln.z * S), exp2f(Aln.w * S)};
  *(float4*)&PC[si] = P;
}

__global__ __launch_bounds__(256) void scanB_k(const float* __restrict__ SE,
                                               const float* __restrict__ PC,
                                               float* __restrict__ SI) {
  long t = (long)blockIdx.x * 256 + threadIdx.x;   // < 98,304
  int n = (int)(t & 15);
  int d = (int)((t >> 4) & 511);
  int bb = (int)(t >> 13);
  float run = 0.f;
  for (int c = 0; c < NCH; ++c) {
    long si = (((long)bb * NCH + c) * 512 + d) * 16 + n;
    SI[si] = run;
    run = fmaf(PC[si], run, SE[si]);
  }
}

__global__ __launch_bounds__(256) void scanC_k(
    const u32* __restrict__ du, const float* __restrict__ xdbl,
    const u16* __restrict__ zs, const float* __restrict__ pk,
    const float* __restrict__ SI, u16* __restrict__ y) {
  __shared__ float bcs[LCH][32];
  int tid = threadIdx.x;
  int wv = tid >> 6, lane = tid & 63;
  int q = lane & 3, dl = lane >> 2;
  int bb = blockIdx.x >> 3, dch = blockIdx.x & 7;
  int br = bb >> 2, b = bb & 3;
  int d = dch * 64 + wv * 16 + dl;
  int c = blockIdx.y;
  long xdb = (long)br * 131072 + (long)b * 32768 + (long)(c * LCH) * 32;
  #pragma unroll
  for (int i = 0; i < 2; ++i) {
    int idx = tid + i * 256;                 // LCH*8 = 512 float4s
    int j = idx >> 3, g = idx & 7;
    *(float4*)&bcs[j][g * 4] = *(const float4*)&xdbl[xdb + j * 32 + g * 4];
  }
  __syncthreads();
  const float* pb = pk + (long)br * BRS;
  float4 Aln = *(const float4*)&pb[35840 + d * 16 + q * 4];
  float Dv = pb[44032 + d];
  long obase = ((long)bb << 19) + (long)(c * LCH) * 512 + d;
  long si = ((((long)bb) * NCH + c) * 512 + d) * 16 + q * 4;
  float4 s = *(const float4*)&SI[si];
  const u32* pdu = du + obase;
  const u16* pzs = zs + obase;
  u16* py = y + obase;
  #pragma unroll 4
  for (int jl = 0; jl < LCH; ++jl) {
    u32 dv = pdu[(long)jl * 512];
    float delta = b2f((u16)dv);
    float uu = b2f((u16)(dv >> 16));
    float w = delta * uu;
    float4 Bv = *(const float4*)&bcs[jl][q * 4];
    float4 Cv = *(const float4*)&bcs[jl][16 + q * 4];
    s.x = fmaf(exp2f(delta * Aln.x), s.x, w * Bv.x);
    s.y = fmaf(exp2f(delta * Aln.y), s.y, w * Bv.y);
    s.z = fmaf(exp2f(delta * Aln.z), s.z, w * Bv.z);
    s.w = fmaf(exp2f(delta * Aln.w), s.w, w * Bv.w);
    float p = s.x * Cv.x;
    p = fmaf(s.y, Cv.y, p);
    p = fmaf(s.z, Cv.z, p);
    p = fmaf(s.w, Cv.w, p);
    DPP_ADD(p, 0xB1);    // + lane^1
    DPP_ADD(p, 0x4E);    // + lane^2
    if (q == 0)
      py[(long)jl * 512] = f2b((p + Dv * uu) * b2f(pzs[(long)jl * 512]));
  }
}

// ---- combine 3 branch outputs -> COMBB bf16 (b,l,512) ---------------------
__global__ __launch_bounds__(256) void combine_k(const u16* __restrict__ y,
                                                 u16* __restrict__ comb) {
  long t = (long)blockIdx.x * 256 + threadIdx.x;   // < 2,097,152
  int d = (int)(t & 511);
  long r = t >> 9;
  int l = (int)(r & 1023);
  int b = (int)(r >> 10);
  int j2 = ((l & 63) << 4) | (l >> 6);
  float v = b2f(y[(((long)b << 10) + l) * 512 + d])
          + b2f(y[(((long)(4 + b) << 10) + (1023 - l)) * 512 + d])
          + b2f(y[(((long)(8 + b) << 10) + j2) * 512 + d]);
  comb[t] = f2b(v);
}

// ---- depthwise 3x3 conv + residual add, NCHW output -----------------------
__global__ __launch_bounds__(256) void dw_k(const u16* __restrict__ xfb,
                                            const float* __restrict__ dww,
                                            const float* __restrict__ dwb,
                                            const float* __restrict__ x,
                                            float* __restrict__ out) {
  __shared__ float plane[1024];
  int bc = blockIdx.x;
  int b = bc >> 8, c = bc & 255;
  int tid = threadIdx.x;
  #pragma unroll
  for (int i = 0; i < 4; ++i) {
    int n = tid + i * 256;
    plane[n] = b2f(xfb[(((long)b << 10) + n) * 256 + c]);
  }
  __syncthreads();
  float wv[9];
  #pragma unroll
  for (int k = 0; k < 9; ++k) wv[k] = dww[c * 9 + k];
  float bb = dwb[c];
  long obase = ((long)(b * 256 + c)) << 10;
  #pragma unroll
  for (int i = 0; i < 4; ++i) {
    int n = tid + i * 256;
    int h = n >> 5, w = n & 31;
    float acc = bb;
    #pragma unroll
    for (int kh = 0; kh < 3; ++kh) {
      int hh = h + kh - 1;
      if ((unsigned)hh >= 32u) continue;
      #pragma unroll
      for (int kw = 0; kw < 3; ++kw) {
        int ww = w + kw - 1;
        if ((unsigned)ww >= 32u) continue;
        acc = fmaf(plane[hh * 32 + ww], wv[kh * 3 + kw], acc);
      }
    }
    out[obase + n] = acc + x[obase + n];
  }
}

// ---------------------------------------------------------------------------
extern "C" void kernel_launch(void* const* d_in, const int* in_sizes, int n_in,
                              void* d_out, int out_size, void* d_ws, size_t ws_size,
                              hipStream_t stream) {
  (void)in_sizes; (void)n_in; (void)out_size; (void)ws_size;
  const float* x    = (const float*)d_in[0];
  const float* p1w  = (const float*)d_in[1];
  const float* p1b  = (const float*)d_in[2];
  const float* p2w  = (const float*)d_in[3];
  const float* p2b  = (const float*)d_in[4];
  const float* nw   = (const float*)d_in[5];
  const float* nb   = (const float*)d_in[6];
  const float* qw   = (const float*)d_in[7];
  const float* qb   = (const float*)d_in[8];
  const float* kw   = (const float*)d_in[9];
  const float* kb   = (const float*)d_in[10];
  const float* vw   = (const float*)d_in[11];
  const float* vb   = (const float*)d_in[12];
  const float* ow   = (const float*)d_in[13];
  const float* ob   = (const float*)d_in[14];
  const float* fc1w = (const float*)d_in[15];
  const float* fc1b = (const float*)d_in[16];
  const float* dww  = (const float*)d_in[17];
  const float* dwb  = (const float*)d_in[18];
  const float* inw  = (const float*)d_in[19];
  const float* cw   = (const float*)d_in[20];
  const float* cb   = (const float*)d_in[21];
  const float* cbw  = (const float*)d_in[22];
  const float* cbb  = (const float*)d_in[23];
  const float* csw  = (const float*)d_in[24];
  const float* csb  = (const float*)d_in[25];
  const float* xpw  = (const float*)d_in[26];
  const float* xpbw = (const float*)d_in[27];
  const float* xpsw = (const float*)d_in[28];
  const float* dtw  = (const float*)d_in[29];
  const float* dtb  = (const float*)d_in[30];
  const float* dtbw = (const float*)d_in[31];
  const float* dtbb = (const float*)d_in[32];
  const float* dtsw = (const float*)d_in[33];
  const float* dtsb = (const float*)d_in[34];
  const float* Alog = (const float*)d_in[35];
  const float* Ablog= (const float*)d_in[36];
  const float* Aslog= (const float*)d_in[37];
  const float* Dv   = (const float*)d_in[38];
  const float* Dbv  = (const float*)d_in[39];
  const float* Dsv  = (const float*)d_in[40];
  const float* outw = (const float*)d_in[41];
  float* out = (float*)d_out;

  float* ws    = (float*)d_ws;
  float* PB    = ws;                          // 133,632
  u16*   WCONV = (u16*)(ws + 140000);         // 294,912 u16
  u16*   WB    = (u16*)(ws + 440000);         // 786,432 u16
  float* QBIAS = ws + 840000;                 // 768
  u16*   XINB  = (u16*)(ws + 850000);         // 1,048,576 u16
  float* R     = ws + 1400000;

  // mamba/scan phase
  u16*    XZB  = (u16*)R;                     // dead after cconv
  u32*    DUB  = (u32*)R;                     // [3][4096][512] u32, 6.3M words
  u16*    Y    = (u16*)(R + 6400000);         // 3.15M words
  u16*    ZS   = (u16*)(R + 12600000);        // 3.15M words
  float*  SE   = R + 15750000;
  float*  PC   = R + 17350000;
  float*  SI   = R + 19000000;
  u16*    XMCB = (u16*)(R + 22050000);        // 3.15M words; dead after fused
  u16*   COMBB = (u16*)(R + 23750000);
  float*  XDBL = R + 25200000;                // [3][4096][32]
  u16*    WMB  = (u16*)(R + 25600000);        // [3][640][512] bf16
  float*  BIA  = R + 26100000;                // [3][640]
  // attn phase (dead before mamba)
  float* XCT   = R + 4300000;
  u16*   XCTB  = (u16*)(R + 5400000);
  u16*   QKVB  = (u16*)(R + 6000000);
  u16*   VT    = (u16*)(R + 7600000);
  float* SC    = R + 8200000;
  u16*   P     = (u16*)(R + 16600000);
  u16*   ATTB  = (u16*)(R + 20900000);
  float* HS    = R + 21500000;
  u16*   XATTB = (u16*)(R + 22600000);
  // tail phase
  u16*   XMBB  = (u16*)R;
  u16*   XM2B  = (u16*)(R + 600000);
  u16*   XPB   = (u16*)(R + 1200000);
  u16*   XFB   = (u16*)(R + 1800000);

  u16* WQKVB = WB;
  u16* OWB   = WB + 196608;
  u16* INWB  = WB + 262144;
  u16* OUTWB = WB + 524288;
  u16* P2WB  = WB + 655360;
  u16* FC1WB = WB + 720896;

  auto bgemm = [&](const u16* A, const u16* Bm, const float* bias,
                   float* OutF, u16* OutH, int M, int N, int K,
                   int lda, int ldb, int ldo, int nz, int zdiv,
                   long a_zb, long a_zh, long b_zb, long b_zh,
                   long o_zb, long o_zh, float alpha, int act,
                   int bias_zb, float* Out2, const u16* Aux) {
    dim3 g(M / 128, N / 128, nz);
    bgemm_k<<<g, 256, 0, stream>>>(A, Bm, bias, OutF, OutH, M, N, K,
                                   lda, ldb, ldo, zdiv, a_zb, a_zh,
                                   b_zb, b_zh, o_zb, o_zh, alpha, act,
                                   bias_zb, Out2, Aux);
  };
  auto bgemm64 = [&](const u16* A, const u16* Bm, const float* bias,
                     float* OutF, u16* OutH, int M, int N, int K,
                     int lda, int ldb, int ldo, int nz, int zdiv,
                     long a_zb, long a_zh, long b_zb, long b_zh,
                     long o_zb, long o_zh, float alpha, int act) {
    dim3 g(M / 64, N / 64, nz);
    bgemm64_k<<<g, 256, 0, stream>>>(A, Bm, bias, OutF, OutH, M, N, K,
                                     lda, ldb, ldo, zdiv, a_zb, a_zh,
                                     b_zb, b_zh, o_zb, o_zh, alpha, act);
  };

  // 0) pack params
  BrP b0 = {cw, cb, xpw, dtw, dtb, Alog, Dv};
  BrP b1 = {cbw, cbb, xpbw, dtbw, dtbb, Ablog, Dbv};
  BrP b2 = {csw, csb, xpsw, dtsw, dtsb, Aslog, Dsv};
  pack_branch_k<<<dim3(174, 3), 256, 0, stream>>>(PB, b0, b1, b2);
  pack_wb_k<<<3075, 256, 0, stream>>>(qw, kw, vw, ow, inw, outw, p2w, fc1w,
                                      qb, kb, vb, WB, QBIAS);
  pack_wc_k<<<2304, 256, 0, stream>>>(p1w, WCONV);
  xin_k<<<4096, 256, 0, stream>>>(x, XINB);
  pack_wmb_k<<<dim3(259, 3), 256, 0, stream>>>(PB, WMB, BIA);
  pack_wdt_k<<<dim3(512, 3), 256, 0, stream>>>(PB, WMB);

  // 1) conv1 (MFMA) -> XCT f32; LN -> XCTB bf16
  conv_mfma_k<<<dim3(64, 4), 256, 0, stream>>>(XINB, WCONV, p1b, XCT, nullptr, 0);
  layernorm_k<<<1024, 256, 0, stream>>>(XCT, nw, nb, XCTB);

  // 2) fused QKV -> QKVB bf16 [4096][768]
  bgemm(XCTB, WQKVB, QBIAS, nullptr, QKVB, 4096, 768, 256, 256, 256, 768,
        1, 1, 0, 0, 0, 0, 0, 0, 1.f, 0, 0, nullptr, nullptr);
  vt_k<<<4096, 256, 0, stream>>>(QKVB, VT);

  // 3) scores f32 = QK^T/sqrt(128); softmax -> P bf16
  bgemm(QKVB, QKVB + 256, nullptr, SC, nullptr, 1024, 1024, 128, 768, 768, 1024,
        8, 2, 786432, 128, 786432, 128, 2097152, 1048576,
        0.08838834764831845f, 0, 0, nullptr, nullptr);
  softmax_k<<<2048, 256, 0, stream>>>(SC, P);

  // 4) att = P @ V^T -> ATTB bf16 [4096][256]  (64-tile: 256 blocks)
  bgemm64(P, VT, nullptr, nullptr, ATTB, 1024, 128, 1024, 1024, 1024, 256,
          8, 2, 2097152, 1048576, 262144, 131072, 262144, 128, 1.f, 0);

  // 5) o-projection -> HS f32; permute -> XATTB bf16
  bgemm64(ATTB, OWB, ob, HS, nullptr, 4096, 256, 256, 256, 256, 256,
          1, 1, 0, 0, 0, 0, 0, 0, 1.f, 0);
  xatt_k<<<4096, 256, 0, stream>>>(HS, XATTB);

  // 6) xz = x_att @ in_w^T -> XZB bf16 [4][1024][1024]
  bgemm(XATTB, INWB, nullptr, nullptr, XZB, 1024, 1024, 256, 256, 256, 1024,
        4, 1, 262144, 0, 0, 0, 1048576, 0, 1.f, 0, 0, nullptr, nullptr);

  // 7) causal conv1d + silu -> XMCB bf16; silu(z) -> ZS bf16
  cconv_k<<<24576, 256, 0, stream>>>(XZB, PB, XMCB, ZS);

  // 8+9) fused B/C + dt GEMM -> XDBL f32 + DUB (bf16 delta | bf16 u)
  bgemm(XMCB, WMB, BIA, (float*)DUB, nullptr, 4096, 640, 512, 512, 512, 0,
        3, 1, 2097152, 0, 327680, 0, 0, 0, 1.f, 4, 640, XDBL, XMCB);

  // 10) chunked selective scan -> Y bf16
  scanA_k<<<dim3(96, NCH), 256, 0, stream>>>(DUB, XDBL, PB, SE, PC);
  scanB_k<<<384, 256, 0, stream>>>(SE, PC, SI);
  scanC_k<<<dim3(96, NCH), 256, 0, stream>>>(DUB, XDBL, ZS, PB, SI, Y);

  // 11) combine -> COMBB bf16
  combine_k<<<8192, 256, 0, stream>>>(Y, COMBB);

  // 12) mamba out projection -> XMBB bf16
  bgemm64(COMBB, OUTWB, nullptr, nullptr, XMBB, 4096, 256, 512, 512, 512, 256,
          1, 1, 0, 0, 0, 0, 0, 0, 1.f, 0);

  // 13) conv1 again (MFMA, NHWC bf16) + relu -> XM2B bf16
  conv_mfma_k<<<dim3(64, 4), 256, 0, stream>>>(XMBB, WCONV, p1b, nullptr, XM2B, 1);

  // 14) proj2 + relu -> XPB bf16
  bgemm64(XM2B, P2WB, p2b, nullptr, XPB, 4096, 256, 256, 256, 256, 256,
          1, 1, 0, 0, 0, 0, 0, 0, 1.f, 1);

  // 15) fc1 -> XFB bf16
  bgemm64(XPB, FC1WB, fc1b, nullptr, XFB, 4096, 256, 256, 256, 256, 256,
          1, 1, 0, 0, 0, 0, 0, 0, 1.f, 0);

  // 16) depthwise 3x3 + residual -> out
  dw_k<<<1024, 256, 0, stream>>>(XFB, dww, dwb, x, out);
}

// Round 10
// 543.315 us; speedup vs baseline: 1.2369x; 1.1003x over previous
//
#include <hip/hip_runtime.h>

// ---------------------------------------------------------------------------
// Att_MambaLayer: bf16-MFMA everywhere + fused BC/dt GEMM (64-tile, bf16 DU)
// + chunked selective scan. B=4, C=256, H=W=32, l=1024, DI=512, DS=16.
// ---------------------------------------------------------------------------

#define LOG2E 1.4426950408889634f
#define NCH 16
#define LCH 64

typedef unsigned short u16;
typedef unsigned int u32;
typedef __attribute__((ext_vector_type(8))) short bf16x8;
typedef __attribute__((ext_vector_type(4))) float f32x4;

__device__ __forceinline__ u16 f2b(float f) {
  u32 u = __builtin_bit_cast(u32, f);
  u32 r = (u + 0x7fffu + ((u >> 16) & 1u)) >> 16;
  return (u16)r;
}
__device__ __forceinline__ float b2f(u16 h) {
  u32 u = ((u32)h) << 16;
  return __builtin_bit_cast(float, u);
}

#define DPP_ADD(p, ctrl)                                                   \
  (p) += __builtin_bit_cast(float, __builtin_amdgcn_update_dpp(            \
             0, __builtin_bit_cast(int, (p)), ctrl, 0xF, 0xF, true))

static const long BRS = 44544;

// ---- param packing --------------------------------------------------------
struct BrP { const float *cw, *cb, *xpw, *dtw, *dtb, *Al, *Dv; };

__global__ __launch_bounds__(256) void pack_branch_k(float* __restrict__ dst0,
                                                     BrP p0, BrP p1, BrP p2) {
  int z = blockIdx.y;
  BrP p = (z == 0) ? p0 : ((z == 1) ? p1 : p2);
  float* dst = dst0 + (long)z * BRS;
  int t = blockIdx.x * 256 + threadIdx.x;
  if (t < 2048) dst[t] = p.cw[t];
  else if (t < 2560) dst[t] = p.cb[t - 2048];
  else if (t < 27136) dst[t] = p.xpw[t - 2560];
  else if (t < 35328) dst[t] = p.dtw[t - 27136];
  else if (t < 35840) dst[t] = p.dtb[t - 35328];
  else if (t < 44032) dst[t] = -expf(p.Al[t - 35840]) * LOG2E;
  else if (t < 44544) dst[t] = p.Dv[t - 44032];
}

__global__ __launch_bounds__(256) void pack_wb_k(
    const float* __restrict__ qw, const float* __restrict__ kw,
    const float* __restrict__ vw, const float* __restrict__ ow,
    const float* __restrict__ inw, const float* __restrict__ outw,
    const float* __restrict__ p2w, const float* __restrict__ fc1w,
    const float* __restrict__ qb, const float* __restrict__ kb,
    const float* __restrict__ vb, u16* __restrict__ WB,
    float* __restrict__ QBIAS) {
  int t = blockIdx.x * 256 + threadIdx.x;   // < 787,200
  if (t < 65536) WB[t] = f2b(qw[t]);
  else if (t < 131072) WB[t] = f2b(kw[t - 65536]);
  else if (t < 196608) WB[t] = f2b(vw[t - 131072]);
  else if (t < 262144) WB[t] = f2b(ow[t - 196608]);
  else if (t < 524288) WB[t] = f2b(inw[t - 262144]);
  else if (t < 655360) WB[t] = f2b(outw[t - 524288]);
  else if (t < 720896) WB[t] = f2b(p2w[t - 655360]);
  else if (t < 786432) WB[t] = f2b(fc1w[t - 720896]);
  else if (t < 787200) {
    int i = t - 786432;
    QBIAS[i] = (i < 256) ? qb[i] : (i < 512 ? kb[i - 256] : vb[i - 512]);
  }
}

// conv weight pack: wc[co][(kh*3+kw)*256+ci] = w[co][ci][kh][kw]
__global__ __launch_bounds__(256) void pack_wc_k(const float* __restrict__ w,
                                                 u16* __restrict__ wc) {
  int t = blockIdx.x * 256 + threadIdx.x;   // < 589,824
  int ci = t & 255, khw = (t >> 8) % 9, co = t / 2304;
  wc[t] = f2b(w[co * 2304 + ci * 9 + khw]);
}

// x input -> shuffled NHWC bf16 (the x_flat permutation)
__global__ __launch_bounds__(256) void xin_k(const float* __restrict__ x,
                                             u16* __restrict__ xin) {
  int t = blockIdx.x * 256 + threadIdx.x;   // < 1,048,576
  int ci = t & 255, w = (t >> 8) & 31, h = (t >> 13) & 31, b = t >> 18;
  int idx = ci * 32 + h;
  xin[t] = f2b(x[((long)b << 18) + ((long)(idx & 255) << 10) +
                 ((idx >> 8) << 5) + w]);
}

// WMB rows 0..31 (B,C from xpw rows 16..47), rows 544..639 zero, bias vector
__global__ __launch_bounds__(256) void pack_wmb_k(const float* __restrict__ PB,
                                                  u16* __restrict__ WMB,
                                                  float* __restrict__ BIA) {
  int z = blockIdx.y;
  int t = blockIdx.x * 256 + threadIdx.x;   // < 66,176
  const float* pb = PB + (long)z * BRS;
  if (t < 16384) {
    int r = t >> 9, k = t & 511;
    WMB[((long)z * 640 + r) * 512 + k] = f2b(pb[2560 + (16 + r) * 512 + k]);
  } else if (t < 65536) {
    int i = t - 16384;
    int r = 544 + (i >> 9), k = i & 511;
    WMB[((long)z * 640 + r) * 512 + k] = 0;
  } else if (t < 66176) {
    int i = t - 65536;   // 0..639
    float v = 0.f;
    if (i >= 32 && i < 544) v = pb[35328 + (i - 32)];
    BIA[(long)z * 640 + i] = v;
  }
}

// W_dt = dtw @ xpw[:16]  -> WMB rows 32..543
__global__ __launch_bounds__(256) void pack_wdt_k(const float* __restrict__ PB,
                                                  u16* __restrict__ WMB) {
  int z = blockIdx.y, d = blockIdx.x;
  const float* pb = PB + (long)z * BRS;
  float dtwv[16];
  #pragma unroll
  for (int r = 0; r < 16; ++r) dtwv[r] = pb[27136 + d * 16 + r];
  #pragma unroll
  for (int i = 0; i < 2; ++i) {
    int k = threadIdx.x + i * 256;
    float acc = 0.f;
    #pragma unroll
    for (int r = 0; r < 16; ++r) acc = fmaf(dtwv[r], pb[2560 + r * 512 + k], acc);
    WMB[((long)z * 640 + 32 + d) * 512 + k] = f2b(acc);
  }
}

// ---- MFMA 3x3 conv --------------------------------------------------------
__global__ __launch_bounds__(256, 2) void conv_mfma_k(
    const u16* __restrict__ in, const u16* __restrict__ wc,
    const float* __restrict__ bias, float* __restrict__ outF,
    u16* __restrict__ outH, int relu) {
  __shared__ u16 ldsA[4][64][8];
  __shared__ u16 ldsB[4][64][8];
  int m0 = blockIdx.x * 64, n0 = blockIdx.y * 64;
  int tid = threadIdx.x;
  int lane = tid & 63, wv = tid >> 6;
  int row = tid & 63, k8 = tid >> 6;
  int l = m0 + row;
  int h = (l >> 5) & 31, w = l & 31;
  int rlo = lane & 15, khl = lane >> 4;
  f32x4 acc[4];
  #pragma unroll
  for (int n = 0; n < 4; ++n) acc[n] = (f32x4){0.f, 0.f, 0.f, 0.f};
  for (int t = 0; t < 72; ++t) {
    int kh = t / 24, r = t % 24, kw = r >> 3, ci0 = (r & 7) << 5;
    __syncthreads();
    bf16x8 av = (bf16x8){0, 0, 0, 0, 0, 0, 0, 0};
    int hh = h + kh - 1, ww = w + kw - 1;
    if ((unsigned)hh < 32u && (unsigned)ww < 32u)
      av = *(const bf16x8*)&in[(long)(l + (kh - 1) * 32 + (kw - 1)) * 256 +
                               ci0 + k8 * 8];
    *(bf16x8*)&ldsA[k8][row][0] = av;
    *(bf16x8*)&ldsB[k8][row][0] =
        *(const bf16x8*)&wc[(long)(n0 + row) * 2304 + t * 32 + k8 * 8];
    __syncthreads();
    bf16x8 af = *(const bf16x8*)&ldsA[khl][wv * 16 + rlo][0];
    #pragma unroll
    for (int n = 0; n < 4; ++n) {
      bf16x8 bf = *(const bf16x8*)&ldsB[khl][n * 16 + rlo][0];
      acc[n] = __builtin_amdgcn_mfma_f32_16x16x32_bf16(af, bf, acc[n], 0, 0, 0);
    }
  }
  int rowb = (lane >> 4) * 4;
  #pragma unroll
  for (int n = 0; n < 4; ++n) {
    int gn = n0 + n * 16 + rlo;
    float bv = bias[gn];
    #pragma unroll
    for (int j = 0; j < 4; ++j) {
      int gm = m0 + wv * 16 + rowb + j;
      float v = acc[n][j] + bv;
      if (relu) v = fmaxf(v, 0.f);
      long oi = (long)gm * 256 + gn;
      if (outH) outH[oi] = f2b(v);
      else outF[oi] = v;
    }
  }
}

// ---- LayerNorm rows of 256 -> bf16 (wave per row) -------------------------
__global__ __launch_bounds__(256) void layernorm_k(const float* __restrict__ x,
                                                   const float* __restrict__ w,
                                                   const float* __restrict__ b,
                                                   u16* __restrict__ o) {
  int row = blockIdx.x * 4 + (threadIdx.x >> 6);
  int lane = threadIdx.x & 63;
  float4 v = ((const float4*)(x + (long)row * 256))[lane];
  float s = v.x + v.y + v.z + v.w;
  #pragma unroll
  for (int m = 32; m; m >>= 1) s += __shfl_xor(s, m);
  float mean = s * (1.f / 256.f);
  float4 dv = {v.x - mean, v.y - mean, v.z - mean, v.w - mean};
  float vs = dv.x * dv.x + dv.y * dv.y + dv.z * dv.z + dv.w * dv.w;
  #pragma unroll
  for (int m = 32; m; m >>= 1) vs += __shfl_xor(vs, m);
  float inv = rsqrtf(vs * (1.f / 256.f) + 1e-5f);
  float4 wv = ((const float4*)w)[lane];
  float4 bv = ((const float4*)b)[lane];
  u32 lo = (u32)f2b(dv.x * inv * wv.x + bv.x) |
           ((u32)f2b(dv.y * inv * wv.y + bv.y) << 16);
  u32 hi = (u32)f2b(dv.z * inv * wv.z + bv.z) |
           ((u32)f2b(dv.w * inv * wv.w + bv.w) << 16);
  ((uint2*)(o + (long)row * 256))[lane] = make_uint2(lo, hi);
}

// ---- softmax rows of 1024: f32 in, bf16 out (wave per row) ----------------
__global__ __launch_bounds__(256) void softmax_k(const float* __restrict__ S,
                                                 u16* __restrict__ P) {
  int row = blockIdx.x * 4 + (threadIdx.x >> 6);
  int lane = threadIdx.x & 63;
  const float4* p = (const float4*)(S + (long)row * 1024);
  float4 v[4];
  float m = -1e30f;
  #pragma unroll
  for (int i = 0; i < 4; ++i) {
    v[i] = p[lane * 4 + i];
    m = fmaxf(m, fmaxf(fmaxf(v[i].x, v[i].y), fmaxf(v[i].z, v[i].w)));
  }
  #pragma unroll
  for (int q = 32; q; q >>= 1) m = fmaxf(m, __shfl_xor(m, q));
  float s = 0.f;
  #pragma unroll
  for (int i = 0; i < 4; ++i) {
    v[i].x = expf(v[i].x - m); v[i].y = expf(v[i].y - m);
    v[i].z = expf(v[i].z - m); v[i].w = expf(v[i].w - m);
    s += v[i].x + v[i].y + v[i].z + v[i].w;
  }
  #pragma unroll
  for (int q = 32; q; q >>= 1) s += __shfl_xor(s, q);
  float inv = 1.f / s;
  uint2* q2 = (uint2*)(P + (long)row * 1024);
  #pragma unroll
  for (int i = 0; i < 4; ++i) {
    u32 lo = (u32)f2b(v[i].x * inv) | ((u32)f2b(v[i].y * inv) << 16);
    u32 hi = (u32)f2b(v[i].z * inv) | ((u32)f2b(v[i].w * inv) << 16);
    q2[lane * 4 + i] = make_uint2(lo, hi);
  }
}

// ---- bf16 MFMA GEMM 128x128 (act: 0 none, 1 relu) -------------------------
__global__ __launch_bounds__(256, 2) void bgemm_k(
    const u16* __restrict__ A, const u16* __restrict__ B,
    const float* __restrict__ bias, float* __restrict__ OutF,
    u16* __restrict__ OutH, int M, int N, int K,
    int lda, int ldb, int ldo, int zdiv,
    long a_zb, long a_zh, long b_zb, long b_zh, long o_zb, long o_zh,
    float alpha, int act) {
  __shared__ u16 ldsA[4][128][8];
  __shared__ u16 ldsB[4][128][8];
  int z = blockIdx.z, zb = z / zdiv, zh = z - zb * zdiv;
  const u16* Ab = A + zb * a_zb + zh * a_zh;
  const u16* Bb = B + zb * b_zb + zh * b_zh;
  long ob = zb * o_zb + zh * o_zh;
  int m0 = blockIdx.x * 128, n0 = blockIdx.y * 128;
  int tid = threadIdx.x;
  int lane = tid & 63, wv = tid >> 6;
  int wr = wv >> 1, wc = wv & 1;
  int r1 = tid & 127, h1 = tid >> 7;
  int r2 = r1, h2 = h1 + 2;
  const u16* a1 = Ab + (long)(m0 + r1) * lda + h1 * 8;
  const u16* a2 = Ab + (long)(m0 + r2) * lda + h2 * 8;
  const u16* b1 = Bb + (long)(n0 + r1) * ldb + h1 * 8;
  const u16* b2 = Bb + (long)(n0 + r2) * ldb + h2 * 8;

  f32x4 acc[4][4];
  #pragma unroll
  for (int i = 0; i < 4; ++i)
    #pragma unroll
    for (int j = 0; j < 4; ++j) acc[i][j] = (f32x4){0.f, 0.f, 0.f, 0.f};

  bf16x8 ra1 = *(const bf16x8*)a1;
  bf16x8 ra2 = *(const bf16x8*)a2;
  bf16x8 rb1 = *(const bf16x8*)b1;
  bf16x8 rb2 = *(const bf16x8*)b2;

  int nt = K >> 5;
  int kh = lane >> 4, rlo = lane & 15;
  for (int t = 0; t < nt; ++t) {
    __syncthreads();
    *(bf16x8*)&ldsA[h1][r1][0] = ra1;
    *(bf16x8*)&ldsA[h2][r2][0] = ra2;
    *(bf16x8*)&ldsB[h1][r1][0] = rb1;
    *(bf16x8*)&ldsB[h2][r2][0] = rb2;
    if (t + 1 < nt) {
      int ko = (t + 1) << 5;
      ra1 = *(const bf16x8*)(a1 + ko);
      ra2 = *(const bf16x8*)(a2 + ko);
      rb1 = *(const bf16x8*)(b1 + ko);
      rb2 = *(const bf16x8*)(b2 + ko);
    }
    __syncthreads();
    bf16x8 af[4], bfr[4];
    #pragma unroll
    for (int m = 0; m < 4; ++m)
      af[m] = *(const bf16x8*)&ldsA[kh][wr * 64 + m * 16 + rlo][0];
    #pragma unroll
    for (int n = 0; n < 4; ++n)
      bfr[n] = *(const bf16x8*)&ldsB[kh][wc * 64 + n * 16 + rlo][0];
    #pragma unroll
    for (int m = 0; m < 4; ++m)
      #pragma unroll
      for (int n = 0; n < 4; ++n)
        acc[m][n] = __builtin_amdgcn_mfma_f32_16x16x32_bf16(af[m], bfr[n],
                                                            acc[m][n], 0, 0, 0);
  }
  int rowb = (lane >> 4) * 4;
  #pragma unroll
  for (int m = 0; m < 4; ++m) {
    #pragma unroll
    for (int n = 0; n < 4; ++n) {
      int gn = n0 + wc * 64 + n * 16 + rlo;
      float bv = bias ? bias[gn] : 0.f;
      #pragma unroll
      for (int j = 0; j < 4; ++j) {
        int gm = m0 + wr * 64 + m * 16 + rowb + j;
        float v = acc[m][n][j] * alpha + bv;
        if (act == 1) v = fmaxf(v, 0.f);
        long oi = ob + (long)gm * ldo + gn;
        if (OutH) OutH[oi] = f2b(v);
        else OutF[oi] = v;
      }
    }
  }
}

// ---- bf16 MFMA GEMM 64x64 --------------------------------------------------
// act: 0 none, 1 relu, 4 fused BC/dt epilogue
//   (Out2=XDBL f32 cols<32; cols 32..543: softplus, pack bf16(delta)|bf16(u))
__global__ __launch_bounds__(256, 2) void bgemm64_k(
    const u16* __restrict__ A, const u16* __restrict__ B,
    const float* __restrict__ bias, float* __restrict__ OutF,
    u16* __restrict__ OutH, int M, int N, int K,
    int lda, int ldb, int ldo, int zdiv,
    long a_zb, long a_zh, long b_zb, long b_zh, long o_zb, long o_zh,
    float alpha, int act, int bias_zb, float* __restrict__ Out2,
    const u16* __restrict__ Aux) {
  __shared__ u16 ldsA[4][64][8];
  __shared__ u16 ldsB[4][64][8];
  int z = blockIdx.z, zb = z / zdiv, zh = z - zb * zdiv;
  const u16* Ab = A + zb * a_zb + zh * a_zh;
  const u16* Bb = B + zb * b_zb + zh * b_zh;
  const float* biasb = bias ? bias + (long)zb * bias_zb : nullptr;
  long ob = zb * o_zb + zh * o_zh;
  int m0 = blockIdx.x * 64, n0 = blockIdx.y * 64;
  int tid = threadIdx.x;
  int lane = tid & 63, wv = tid >> 6;
  int row = tid & 63, k8 = tid >> 6;
  int rlo = lane & 15, khl = lane >> 4;
  const u16* pa = Ab + (long)(m0 + row) * lda + k8 * 8;
  const u16* pb = Bb + (long)(n0 + row) * ldb + k8 * 8;
  f32x4 acc[4];
  #pragma unroll
  for (int n = 0; n < 4; ++n) acc[n] = (f32x4){0.f, 0.f, 0.f, 0.f};
  bf16x8 ra = *(const bf16x8*)pa;
  bf16x8 rb = *(const bf16x8*)pb;
  int nt = K >> 5;
  for (int t = 0; t < nt; ++t) {
    __syncthreads();
    *(bf16x8*)&ldsA[k8][row][0] = ra;
    *(bf16x8*)&ldsB[k8][row][0] = rb;
    if (t + 1 < nt) {
      int ko = (t + 1) << 5;
      ra = *(const bf16x8*)(pa + ko);
      rb = *(const bf16x8*)(pb + ko);
    }
    __syncthreads();
    bf16x8 af = *(const bf16x8*)&ldsA[khl][wv * 16 + rlo][0];
    #pragma unroll
    for (int n = 0; n < 4; ++n) {
      bf16x8 bf = *(const bf16x8*)&ldsB[khl][n * 16 + rlo][0];
      acc[n] = __builtin_amdgcn_mfma_f32_16x16x32_bf16(af, bf, acc[n], 0, 0, 0);
    }
  }
  int rowb = (lane >> 4) * 4;
  #pragma unroll
  for (int n = 0; n < 4; ++n) {
    int gn = n0 + n * 16 + rlo;
    float bv = biasb ? biasb[gn] : 0.f;
    #pragma unroll
    for (int j = 0; j < 4; ++j) {
      int gm = m0 + wv * 16 + rowb + j;
      float v = acc[n][j] * alpha + bv;
      if (act == 4) {
        if (gn < 32) {
          Out2[(long)(zb * 4096 + gm) * 32 + gn] = v;
        } else if (gn < 544) {
          float sp = (v > 30.f) ? v : log1pf(expf(v));
          long di = (long)(zb * 4096 + gm) * 512 + (gn - 32);
          ((u32*)OutF)[di] = (u32)f2b(sp) | ((u32)Aux[di] << 16);
        }
      } else {
        if (act == 1) v = fmaxf(v, 0.f);
        long oi = ob + (long)gm * ldo + gn;
        if (OutH) OutH[oi] = f2b(v);
        else OutF[oi] = v;
      }
    }
  }
}

// ---- V transpose ----------------------------------------------------------
__global__ __launch_bounds__(256) void vt_k(const u16* __restrict__ qkv,
                                            u16* __restrict__ vt) {
  int t = blockIdx.x * 256 + threadIdx.x;    // < 1,048,576
  int j = t & 1023, d = (t >> 10) & 127, bh = t >> 17;
  int b = bh >> 1, h = bh & 1;
  vt[t] = qkv[((long)(b * 1024 + j)) * 768 + 512 + h * 128 + d];
}

// ---- x_att permute --------------------------------------------------------
__global__ __launch_bounds__(256) void xatt_k(const float* __restrict__ hs,
                                              u16* __restrict__ xa) {
  int t = blockIdx.x * 256 + threadIdx.x;    // < 1,048,576
  int dm = t & 255, l = (t >> 8) & 1023, b = t >> 18;
  xa[t] = f2b(hs[((long)b << 18) + dm * 1024 + l]);
}

// ---- branch sequence index map --------------------------------------------
__device__ __forceinline__ int brmap(int br, int j) {
  if (br == 0) return j;
  if (br == 1) return 1023 - j;
  return ((j & 15) << 6) | (j >> 4);
}

// ---- causal conv1d (k=4) + silu -> bf16; silu(z) -> bf16 ------------------
__global__ __launch_bounds__(256) void cconv_k(const u16* __restrict__ xzb,
                                               const float* __restrict__ pk,
                                               u16* __restrict__ xmcb,
                                               u16* __restrict__ zs) {
  long t = (long)blockIdx.x * 256 + threadIdx.x;   // < 6,291,456
  int d = (int)(t & 511);
  long r = t >> 9;
  int j = (int)(r & 1023);
  int bb = (int)(r >> 10);
  int b = bb & 3, br = bb >> 2;
  const float* pb = pk + (long)br * BRS;
  float acc = pb[2048 + d];
  #pragma unroll
  for (int tap = 0; tap < 4; ++tap) {
    int jj = j - 3 + tap;
    if (jj >= 0) {
      int l = brmap(br, jj);
      acc = fmaf(b2f(xzb[(((long)b << 10) + l) * 1024 + d]), pb[d * 4 + tap],
                 acc);
    }
  }
  float sig = 1.f / (1.f + expf(-acc));
  xmcb[t] = f2b(acc * sig);
  int l = brmap(br, j);
  float zv = b2f(xzb[(((long)b << 10) + l) * 1024 + 512 + d]);
  zs[t] = f2b(zv / (1.f + expf(-zv)));
}

// ---- chunked selective scan, 4 lanes/row x 4 states/lane ------------------
// DUB word: lo16 = bf16(delta), hi16 = bf16(u).
__global__ __launch_bounds__(256) void scanA_k(
    const u32* __restrict__ du, const float* __restrict__ xdbl,
    const float* __restrict__ pk, float* __restrict__ SE,
    float* __restrict__ PC) {
  __shared__ float bs[LCH][16];
  int tid = threadIdx.x;
  int wv = tid >> 6, lane = tid & 63;
  int q = lane & 3, dl = lane >> 2;
  int bb = blockIdx.x >> 3, dch = blockIdx.x & 7;
  int br = bb >> 2, b = bb & 3;
  int d = dch * 64 + wv * 16 + dl;
  int c = blockIdx.y;
  long xdb = (long)br * 131072 + (long)b * 32768 + (long)(c * LCH) * 32;
  {
    int j = tid >> 2, g = tid & 3;   // LCH*4 = 256 float4s
    *(float4*)&bs[j][g * 4] = *(const float4*)&xdbl[xdb + j * 32 + g * 4];
  }
  __syncthreads();
  const float* pb = pk + (long)br * BRS;
  float4 Aln = *(const float4*)&pb[35840 + d * 16 + q * 4];
  long obase = ((long)bb << 19) + (long)(c * LCH) * 512 + d;
  const u32* pdu = du + obase;
  float4 s = {0.f, 0.f, 0.f, 0.f};
  float S = 0.f;
  #pragma unroll 4
  for (int jl = 0; jl < LCH; ++jl) {
    u32 dv = pdu[(long)jl * 512];
    float delta = b2f((u16)dv);
    float uu = b2f((u16)(dv >> 16));
    float w = delta * uu;
    float4 Bv = *(const float4*)&bs[jl][q * 4];
    s.x = fmaf(exp2f(delta * Aln.x), s.x, w * Bv.x);
    s.y = fmaf(exp2f(delta * Aln.y), s.y, w * Bv.y);
    s.z = fmaf(exp2f(delta * Aln.z), s.z, w * Bv.z);
    s.w = fmaf(exp2f(delta * Aln.w), s.w, w * Bv.w);
    S += delta;
  }
  long si = ((((long)bb) * NCH + c) * 512 + d) * 16 + q * 4;
  *(float4*)&SE[si] = s;
  float4 P = {exp2f(Aln.x * S), exp2f(Aln.y * S),
              exp2f(Aln.z * S), exp2f(Aln.w * S)};
  *(float4*)&PC[si] = P;
}

__global__ __launch_bounds__(256) void scanB_k(const float* __restrict__ SE,
                                               const float* __restrict__ PC,
                                               float* __restrict__ SI) {
  long t = (long)blockIdx.x * 256 + threadIdx.x;   // < 98,304
  int n = (int)(t & 15);
  int d = (int)((t >> 4) & 511);
  int bb = (int)(t >> 13);
  float run = 0.f;
  for (int c = 0; c < NCH; ++c) {
    long si = (((long)bb * NCH + c) * 512 + d) * 16 + n;
    SI[si] = run;
    run = fmaf(PC[si], run, SE[si]);
  }
}

__global__ __launch_bounds__(256) void scanC_k(
    const u32* __restrict__ du, const float* __restrict__ xdbl,
    const u16* __restrict__ zs, const float* __restrict__ pk,
    const float* __restrict__ SI, u16* __restrict__ y) {
  __shared__ float bcs[LCH][32];
  int tid = threadIdx.x;
  int wv = tid >> 6, lane = tid & 63;
  int q = lane & 3, dl = lane >> 2;
  int bb = blockIdx.x >> 3, dch = blockIdx.x & 7;
  int br = bb >> 2, b = bb & 3;
  int d = dch * 64 + wv * 16 + dl;
  int c = blockIdx.y;
  long xdb = (long)br * 131072 + (long)b * 32768 + (long)(c * LCH) * 32;
  #pragma unroll
  for (int i = 0; i < 2; ++i) {
    int idx = tid + i * 256;                 // LCH*8 = 512 float4s
    int j = idx >> 3, g = idx & 7;
    *(float4*)&bcs[j][g * 4] = *(const float4*)&xdbl[xdb + j * 32 + g * 4];
  }
  __syncthreads();
  const float* pb = pk + (long)br * BRS;
  float4 Aln = *(const float4*)&pb[35840 + d * 16 + q * 4];
  float Dv = pb[44032 + d];
  long obase = ((long)bb << 19) + (long)(c * LCH) * 512 + d;
  long si = ((((long)bb) * NCH + c) * 512 + d) * 16 + q * 4;
  float4 s = *(const float4*)&SI[si];
  const u32* pdu = du + obase;
  const u16* pzs = zs + obase;
  u16* py = y + obase;
  #pragma unroll 4
  for (int jl = 0; jl < LCH; ++jl) {
    u32 dv = pdu[(long)jl * 512];
    float delta = b2f((u16)dv);
    float uu = b2f((u16)(dv >> 16));
    float w = delta * uu;
    float4 Bv = *(const float4*)&bcs[jl][q * 4];
    float4 Cv = *(const float4*)&bcs[jl][16 + q * 4];
    s.x = fmaf(exp2f(delta * Aln.x), s.x, w * Bv.x);
    s.y = fmaf(exp2f(delta * Aln.y), s.y, w * Bv.y);
    s.z = fmaf(exp2f(delta * Aln.z), s.z, w * Bv.z);
    s.w = fmaf(exp2f(delta * Aln.w), s.w, w * Bv.w);
    float p = s.x * Cv.x;
    p = fmaf(s.y, Cv.y, p);
    p = fmaf(s.z, Cv.z, p);
    p = fmaf(s.w, Cv.w, p);
    DPP_ADD(p, 0xB1);    // + lane^1
    DPP_ADD(p, 0x4E);    // + lane^2
    if (q == 0)
      py[(long)jl * 512] = f2b((p + Dv * uu) * b2f(pzs[(long)jl * 512]));
  }
}

// ---- combine 3 branch outputs -> COMBB bf16 (b,l,512) ---------------------
__global__ __launch_bounds__(256) void combine_k(const u16* __restrict__ y,
                                                 u16* __restrict__ comb) {
  long t = (long)blockIdx.x * 256 + threadIdx.x;   // < 2,097,152
  int d = (int)(t & 511);
  long r = t >> 9;
  int l = (int)(r & 1023);
  int b = (int)(r >> 10);
  int j2 = ((l & 63) << 4) | (l >> 6);
  float v = b2f(y[(((long)b << 10) + l) * 512 + d])
          + b2f(y[(((long)(4 + b) << 10) + (1023 - l)) * 512 + d])
          + b2f(y[(((long)(8 + b) << 10) + j2) * 512 + d]);
  comb[t] = f2b(v);
}

// ---- depthwise 3x3 conv + residual add, NCHW output -----------------------
__global__ __launch_bounds__(256) void dw_k(const u16* __restrict__ xfb,
                                            const float* __restrict__ dww,
                                            const float* __restrict__ dwb,
                                            const float* __restrict__ x,
                                            float* __restrict__ out) {
  __shared__ float plane[1024];
  int bc = blockIdx.x;
  int b = bc >> 8, c = bc & 255;
  int tid = threadIdx.x;
  #pragma unroll
  for (int i = 0; i < 4; ++i) {
    int n = tid + i * 256;
    plane[n] = b2f(xfb[(((long)b << 10) + n) * 256 + c]);
  }
  __syncthreads();
  float wv[9];
  #pragma unroll
  for (int k = 0; k < 9; ++k) wv[k] = dww[c * 9 + k];
  float bb = dwb[c];
  long obase = ((long)(b * 256 + c)) << 10;
  #pragma unroll
  for (int i = 0; i < 4; ++i) {
    int n = tid + i * 256;
    int h = n >> 5, w = n & 31;
    float acc = bb;
    #pragma unroll
    for (int kh = 0; kh < 3; ++kh) {
      int hh = h + kh - 1;
      if ((unsigned)hh >= 32u) continue;
      #pragma unroll
      for (int kw = 0; kw < 3; ++kw) {
        int ww = w + kw - 1;
        if ((unsigned)ww >= 32u) continue;
        acc = fmaf(plane[hh * 32 + ww], wv[kh * 3 + kw], acc);
      }
    }
    out[obase + n] = acc + x[obase + n];
  }
}

// ---------------------------------------------------------------------------
extern "C" void kernel_launch(void* const* d_in, const int* in_sizes, int n_in,
                              void* d_out, int out_size, void* d_ws, size_t ws_size,
                              hipStream_t stream) {
  (void)in_sizes; (void)n_in; (void)out_size; (void)ws_size;
  const float* x    = (const float*)d_in[0];
  const float* p1w  = (const float*)d_in[1];
  const float* p1b  = (const float*)d_in[2];
  const float* p2w  = (const float*)d_in[3];
  const float* p2b  = (const float*)d_in[4];
  const float* nw   = (const float*)d_in[5];
  const float* nb   = (const float*)d_in[6];
  const float* qw   = (const float*)d_in[7];
  const float* qb   = (const float*)d_in[8];
  const float* kw   = (const float*)d_in[9];
  const float* kb   = (const float*)d_in[10];
  const float* vw   = (const float*)d_in[11];
  const float* vb   = (const float*)d_in[12];
  const float* ow   = (const float*)d_in[13];
  const float* ob   = (const float*)d_in[14];
  const float* fc1w = (const float*)d_in[15];
  const float* fc1b = (const float*)d_in[16];
  const float* dww  = (const float*)d_in[17];
  const float* dwb  = (const float*)d_in[18];
  const float* inw  = (const float*)d_in[19];
  const float* cw   = (const float*)d_in[20];
  const float* cb   = (const float*)d_in[21];
  const float* cbw  = (const float*)d_in[22];
  const float* cbb  = (const float*)d_in[23];
  const float* csw  = (const float*)d_in[24];
  const float* csb  = (const float*)d_in[25];
  const float* xpw  = (const float*)d_in[26];
  const float* xpbw = (const float*)d_in[27];
  const float* xpsw = (const float*)d_in[28];
  const float* dtw  = (const float*)d_in[29];
  const float* dtb  = (const float*)d_in[30];
  const float* dtbw = (const float*)d_in[31];
  const float* dtbb = (const float*)d_in[32];
  const float* dtsw = (const float*)d_in[33];
  const float* dtsb = (const float*)d_in[34];
  const float* Alog = (const float*)d_in[35];
  const float* Ablog= (const float*)d_in[36];
  const float* Aslog= (const float*)d_in[37];
  const float* Dv   = (const float*)d_in[38];
  const float* Dbv  = (const float*)d_in[39];
  const float* Dsv  = (const float*)d_in[40];
  const float* outw = (const float*)d_in[41];
  float* out = (float*)d_out;

  float* ws    = (float*)d_ws;
  float* PB    = ws;                          // 133,632
  u16*   WCONV = (u16*)(ws + 140000);         // 294,912 u16
  u16*   WB    = (u16*)(ws + 440000);         // 786,432 u16
  float* QBIAS = ws + 840000;                 // 768
  u16*   XINB  = (u16*)(ws + 850000);         // 1,048,576 u16
  float* R     = ws + 1400000;

  // mamba/scan phase
  u16*    XZB  = (u16*)R;                     // dead after cconv
  u32*    DUB  = (u32*)R;                     // [3][4096][512] u32, 6.3M words
  u16*    Y    = (u16*)(R + 6400000);         // 3.15M words
  u16*    ZS   = (u16*)(R + 12600000);        // 3.15M words
  float*  SE   = R + 15750000;
  float*  PC   = R + 17350000;
  float*  SI   = R + 19000000;
  u16*    XMCB = (u16*)(R + 22050000);        // 3.15M words; dead after fused
  u16*   COMBB = (u16*)(R + 23750000);
  float*  XDBL = R + 25200000;                // [3][4096][32]
  u16*    WMB  = (u16*)(R + 25600000);        // [3][640][512] bf16
  float*  BIA  = R + 26100000;                // [3][640]
  // attn phase (dead before mamba)
  float* XCT   = R + 4300000;
  u16*   XCTB  = (u16*)(R + 5400000);
  u16*   QKVB  = (u16*)(R + 6000000);
  u16*   VT    = (u16*)(R + 7600000);
  float* SC    = R + 8200000;
  u16*   P     = (u16*)(R + 16600000);
  u16*   ATTB  = (u16*)(R + 20900000);
  float* HS    = R + 21500000;
  u16*   XATTB = (u16*)(R + 22600000);
  // tail phase
  u16*   XMBB  = (u16*)R;
  u16*   XM2B  = (u16*)(R + 600000);
  u16*   XPB   = (u16*)(R + 1200000);
  u16*   XFB   = (u16*)(R + 1800000);

  u16* WQKVB = WB;
  u16* OWB   = WB + 196608;
  u16* INWB  = WB + 262144;
  u16* OUTWB = WB + 524288;
  u16* P2WB  = WB + 655360;
  u16* FC1WB = WB + 720896;

  auto bgemm = [&](const u16* A, const u16* Bm, const float* bias,
                   float* OutF, u16* OutH, int M, int N, int K,
                   int lda, int ldb, int ldo, int nz, int zdiv,
                   long a_zb, long a_zh, long b_zb, long b_zh,
                   long o_zb, long o_zh, float alpha, int act) {
    dim3 g(M / 128, N / 128, nz);
    bgemm_k<<<g, 256, 0, stream>>>(A, Bm, bias, OutF, OutH, M, N, K,
                                   lda, ldb, ldo, zdiv, a_zb, a_zh,
                                   b_zb, b_zh, o_zb, o_zh, alpha, act);
  };
  auto bgemm64 = [&](const u16* A, const u16* Bm, const float* bias,
                     float* OutF, u16* OutH, int M, int N, int K,
                     int lda, int ldb, int ldo, int nz, int zdiv,
                     long a_zb, long a_zh, long b_zb, long b_zh,
                     long o_zb, long o_zh, float alpha, int act,
                     int bias_zb, float* Out2, const u16* Aux) {
    dim3 g(M / 64, N / 64, nz);
    bgemm64_k<<<g, 256, 0, stream>>>(A, Bm, bias, OutF, OutH, M, N, K,
                                     lda, ldb, ldo, zdiv, a_zb, a_zh,
                                     b_zb, b_zh, o_zb, o_zh, alpha, act,
                                     bias_zb, Out2, Aux);
  };

  // 0) pack params
  BrP b0 = {cw, cb, xpw, dtw, dtb, Alog, Dv};
  BrP b1 = {cbw, cbb, xpbw, dtbw, dtbb, Ablog, Dbv};
  BrP b2 = {csw, csb, xpsw, dtsw, dtsb, Aslog, Dsv};
  pack_branch_k<<<dim3(174, 3), 256, 0, stream>>>(PB, b0, b1, b2);
  pack_wb_k<<<3075, 256, 0, stream>>>(qw, kw, vw, ow, inw, outw, p2w, fc1w,
                                      qb, kb, vb, WB, QBIAS);
  pack_wc_k<<<2304, 256, 0, stream>>>(p1w, WCONV);
  xin_k<<<4096, 256, 0, stream>>>(x, XINB);
  pack_wmb_k<<<dim3(259, 3), 256, 0, stream>>>(PB, WMB, BIA);
  pack_wdt_k<<<dim3(512, 3), 256, 0, stream>>>(PB, WMB);

  // 1) conv1 (MFMA) -> XCT f32; LN -> XCTB bf16
  conv_mfma_k<<<dim3(64, 4), 256, 0, stream>>>(XINB, WCONV, p1b, XCT, nullptr, 0);
  layernorm_k<<<1024, 256, 0, stream>>>(XCT, nw, nb, XCTB);

  // 2) fused QKV -> QKVB bf16 [4096][768]  (64-tile: 768 blocks)
  bgemm64(XCTB, WQKVB, QBIAS, nullptr, QKVB, 4096, 768, 256, 256, 256, 768,
          1, 1, 0, 0, 0, 0, 0, 0, 1.f, 0, 0, nullptr, nullptr);
  vt_k<<<4096, 256, 0, stream>>>(QKVB, VT);

  // 3) scores f32 = QK^T/sqrt(128); softmax -> P bf16
  bgemm(QKVB, QKVB + 256, nullptr, SC, nullptr, 1024, 1024, 128, 768, 768, 1024,
        8, 2, 786432, 128, 786432, 128, 2097152, 1048576,
        0.08838834764831845f, 0);
  softmax_k<<<2048, 256, 0, stream>>>(SC, P);

  // 4) att = P @ V^T -> ATTB bf16 [4096][256]  (64-tile: 256 blocks)
  bgemm64(P, VT, nullptr, nullptr, ATTB, 1024, 128, 1024, 1024, 1024, 256,
          8, 2, 2097152, 1048576, 262144, 131072, 262144, 128, 1.f, 0,
          0, nullptr, nullptr);

  // 5) o-projection -> HS f32; permute -> XATTB bf16
  bgemm64(ATTB, OWB, ob, HS, nullptr, 4096, 256, 256, 256, 256, 256,
          1, 1, 0, 0, 0, 0, 0, 0, 1.f, 0, 0, nullptr, nullptr);
  xatt_k<<<4096, 256, 0, stream>>>(HS, XATTB);

  // 6) xz = x_att @ in_w^T -> XZB bf16 [4][1024][1024]  (64-tile: 1024 blocks)
  bgemm64(XATTB, INWB, nullptr, nullptr, XZB, 1024, 1024, 256, 256, 256, 1024,
          4, 1, 262144, 0, 0, 0, 1048576, 0, 1.f, 0, 0, nullptr, nullptr);

  // 7) causal conv1d + silu -> XMCB bf16; silu(z) -> ZS bf16
  cconv_k<<<24576, 256, 0, stream>>>(XZB, PB, XMCB, ZS);

  // 8+9) fused B/C + dt GEMM (64-tile, N=576 -> 1728 blocks)
  //      -> XDBL f32 + DUB (bf16 delta | bf16 u)
  bgemm64(XMCB, WMB, BIA, (float*)DUB, nullptr, 4096, 576, 512, 512, 512, 0,
          3, 1, 2097152, 0, 327680, 0, 0, 0, 1.f, 4, 640, XDBL, XMCB);

  // 10) chunked selective scan -> Y bf16
  scanA_k<<<dim3(96, NCH), 256, 0, stream>>>(DUB, XDBL, PB, SE, PC);
  scanB_k<<<384, 256, 0, stream>>>(SE, PC, SI);
  scanC_k<<<dim3(96, NCH), 256, 0, stream>>>(DUB, XDBL, ZS, PB, SI, Y);

  // 11) combine -> COMBB bf16
  combine_k<<<8192, 256, 0, stream>>>(Y, COMBB);

  // 12) mamba out projection -> XMBB bf16
  bgemm64(COMBB, OUTWB, nullptr, nullptr, XMBB, 4096, 256, 512, 512, 512, 256,
          1, 1, 0, 0, 0, 0, 0, 0, 1.f, 0, 0, nullptr, nullptr);

  // 13) conv1 again (MFMA, NHWC bf16) + relu -> XM2B bf16
  conv_mfma_k<<<dim3(64, 4), 256, 0, stream>>>(XMBB, WCONV, p1b, nullptr, XM2B, 1);

  // 14) proj2 + relu -> XPB bf16
  bgemm64(XM2B, P2WB, p2b, nullptr, XPB, 4096, 256, 256, 256, 256, 256,
          1, 1, 0, 0, 0, 0, 0, 0, 1.f, 1, 0, nullptr, nullptr);

  // 15) fc1 -> XFB bf16
  bgemm64(XPB, FC1WB, fc1b, nullptr, XFB, 4096, 256, 256, 256, 256, 256,
          1, 1, 0, 0, 0, 0, 0, 0, 1.f, 0, 0, nullptr, nullptr);

  // 16) depthwise 3x3 + residual -> out
  dw_k<<<1024, 256, 0, stream>>>(XFB, dww, dwb, x, out);
}